// Round 9
// baseline (283.435 us; speedup 1.0000x reference)
//
#include <hip/hip_runtime.h>
#include <hip/hip_bf16.h>
#include <stdint.h>

// ---------------- types / helpers ----------------
typedef __attribute__((ext_vector_type(8))) short bf16x8;   // 8 bf16 = 4 VGPRs
typedef __attribute__((ext_vector_type(4))) float f32x4;

__device__ __forceinline__ unsigned short f2bf(float f) {
  unsigned int u = __float_as_uint(f);
  u += 0x7fff + ((u >> 16) & 1);   // round-to-nearest-even
  return (unsigned short)(u >> 16);
}

__device__ __forceinline__ void gload16(const void* g, void* l) {
  __builtin_amdgcn_global_load_lds(
      (const __attribute__((address_space(1))) void*)g,
      (__attribute__((address_space(3))) void*)l, 16, 0, 0);
}

// ---------------- problem constants ----------------
#define Bsz   8192
#define D_IN  1024
#define D_H   2048
#define D_BOT 512
#define D_EXP 1024
#define N_CLS 10

// ---------------- routing: hist + scan + assign in ONE block ----------------
__global__ __launch_bounds__(1024) void k_route(const int* __restrict__ lab,
                                                int* __restrict__ counts,
                                                int* __restrict__ starts,
                                                int* __restrict__ perm) {
  __shared__ int scnt[N_CLS], scur[N_CLS];
  const int t = threadIdx.x;
  if (t < N_CLS) scnt[t] = 0;
  __syncthreads();
  int myl[8];
#pragma unroll
  for (int i = 0; i < 8; ++i) {
    myl[i] = lab[t * 8 + i];
    atomicAdd(&scnt[myl[i]], 1);
  }
  __syncthreads();
  if (t == 0) {
    int s = 0;
    for (int e = 0; e < N_CLS; ++e) {
      starts[e] = s; scur[e] = s; counts[e] = scnt[e]; s += scnt[e];
    }
  }
  __syncthreads();
#pragma unroll
  for (int i = 0; i < 8; ++i) {
    int p = atomicAdd(&scur[myl[i]], 1);
    perm[p] = t * 8 + i;
  }
}

// fp32 -> bf16 elementwise (8 elems/thread)
__global__ void k_cvt(const float* __restrict__ in, unsigned short* __restrict__ out) {
  int i = (blockIdx.x * blockDim.x + threadIdx.x) * 8;
  const float4* p = (const float4*)(in + i);
  float4 a = p[0], b = p[1];
  uint4 o;
  o.x = (unsigned)f2bf(a.x) | ((unsigned)f2bf(a.y) << 16);
  o.y = (unsigned)f2bf(a.z) | ((unsigned)f2bf(a.w) << 16);
  o.z = (unsigned)f2bf(b.x) | ((unsigned)f2bf(b.y) << 16);
  o.w = (unsigned)f2bf(b.z) | ((unsigned)f2bf(b.w) << 16);
  *(uint4*)(out + i) = o;
}

// W [K][N] fp32  ->  WT [N][K] bf16   (tiled transpose; K,N multiples of 32)
__global__ void k_transpose_cvt(const float* __restrict__ in, unsigned short* __restrict__ out,
                                int K, int N) {
  __shared__ float tile[32][33];
  size_t eoff = (size_t)blockIdx.z * K * N;
  in  += eoff;
  out += eoff;
  int n0 = blockIdx.x * 32, k0 = blockIdx.y * 32;
  int tx = threadIdx.x, ty = threadIdx.y;   // 32 x 8
#pragma unroll
  for (int i = 0; i < 4; i++) {
    int k = ty + i * 8;
    tile[k][tx] = in[(size_t)(k0 + k) * N + n0 + tx];
  }
  __syncthreads();
#pragma unroll
  for (int i = 0; i < 4; i++) {
    int n = ty + i * 8;
    out[(size_t)(n0 + n) * K + k0 + tx] = f2bf(tile[tx][n]);
  }
}

// ============ 256x256 GEMM (m201 geometry): C = act(A * WT^T + b) ============
// 8 waves (2M x 4N), per-wave 128x64, BK=64. Double-buffered swizzled LDS
// (128 KB). One barrier + vmcnt(0) per K-tile; stage kt+1 issued right after
// the barrier (full-iteration latency cover); NO intra-tile lockstep barriers.
// Rationale (R4-R8): schedule-invariant ~53us => LLC-traffic bound; 256x256
// halves B-panel re-reads (B traffic x(M/256) instead of x(M/128)).
template <bool RELU, bool BF16OUT>
__global__ __launch_bounds__(512, 2) void k_gemm8(
    const unsigned short* __restrict__ A,   // [M][K] bf16
    const unsigned short* __restrict__ WT,  // [N][K] bf16
    const float* __restrict__ bias,         // [N] fp32
    void* __restrict__ Cv,                  // [M][N] bf16 or fp32
    int M, int N, int K) {
  constexpr int BM = 256, BN = 256;

  // XCD-bijective chunk swizzle (m204), y-fastest work order (R7 form)
  const int nby = gridDim.y;
  const int nwg = gridDim.x * nby;
  int orig = blockIdx.x + gridDim.x * blockIdx.y;
  int q = nwg >> 3, r = nwg & 7;
  int xcd = orig & 7, idx = orig >> 3;
  int wg = (xcd < r ? xcd * (q + 1) : r * (q + 1) + (xcd - r) * q) + idx;
  int bx = wg / nby, by = wg % nby;
  const int m0 = bx * BM, n0 = by * BN;

  __shared__ __align__(16) unsigned short As[2][BM * 64];   // 2 x 32 KB
  __shared__ __align__(16) unsigned short Bs[2][BN * 64];   // 2 x 32 KB

  const int t = threadIdx.x;
  const int l = t & 63;
  const int w = t >> 6;
  const int wm = w >> 2, wn = w & 3;   // 2M x 4N waves; per-wave 128x64

  // staging: 8 chunks/K-tile (4 A + 4 B), chunk = 64 rows x 128 B = 8 KB,
  // 512 threads x 16 B cover one chunk. thread t: row = t>>3, slot=(t&7)^(row&7)
  const int rl = t >> 3;
  const int sl16 = (t & 7) ^ (rl & 7);
  const unsigned short* asrc[4];
  const unsigned short* bsrc[4];
#pragma unroll
  for (int i = 0; i < 4; ++i) {
    asrc[i] = A + (size_t)(m0 + i * 64 + rl) * K + sl16 * 8;
    bsrc[i] = WT + (size_t)(n0 + i * 64 + rl) * K + sl16 * 8;
  }
  const int dst = t * 8;

  auto STAGE = [&](int kt, int buf) {
#pragma unroll
    for (int i = 0; i < 4; ++i)
      gload16(asrc[i] + kt * 64, &As[buf][i * 4096 + dst]);
#pragma unroll
    for (int i = 0; i < 4; ++i)
      gload16(bsrc[i] + kt * 64, &Bs[buf][i * 4096 + dst]);
  };

  f32x4 acc[8][4] = {};     // [fm][fn] -- 128 VGPR
  bf16x8 bq[4][2];          // B frags [fn][ks], whole K-tile
  bf16x8 af[2];             // A frags for current fm [ks]

  const int la = l & 15;
  const int ko = l >> 4;    // 0..3
  const int arow0 = wm * 128 + la;
  const int brow0 = wn * 64 + la;

  const int nt = K / 64;
  STAGE(0, 0);

  for (int kt = 0; kt < nt; ++kt) {
    const int cur = kt & 1;
    const char* Ab = (const char*)As[cur];
    const char* Bb = (const char*)Bs[cur];

    asm volatile("s_waitcnt vmcnt(0)" ::: "memory");   // tile kt landed (issued 1 iter ago)
    __builtin_amdgcn_s_barrier();                      // + prev readers of buf^1 done
    if (kt + 1 < nt) STAGE(kt + 1, cur ^ 1);           // full-iter latency cover
    __builtin_amdgcn_sched_barrier(0);

    // B frags once per K-tile (8 ds_read_b128, conflict-free swizzle)
#pragma unroll
    for (int fn = 0; fn < 4; ++fn)
#pragma unroll
      for (int ks = 0; ks < 2; ++ks) {
        int row = brow0 + fn * 16;
        int s = ks * 4 + ko;
        bq[fn][ks] = *(const bf16x8*)(Bb + (row << 7) + ((s ^ (row & 7)) << 4));
      }

#pragma unroll
    for (int fm = 0; fm < 8; ++fm) {
      int row = arow0 + fm * 16;
#pragma unroll
      for (int ks = 0; ks < 2; ++ks) {
        int s = ks * 4 + ko;
        af[ks] = *(const bf16x8*)(Ab + (row << 7) + ((s ^ (row & 7)) << 4));
      }
      __builtin_amdgcn_s_setprio(1);
#pragma unroll
      for (int fn = 0; fn < 4; ++fn)
#pragma unroll
        for (int ks = 0; ks < 2; ++ks)
          acc[fm][fn] = __builtin_amdgcn_mfma_f32_16x16x32_bf16(
              af[ks], bq[fn][ks], acc[fm][fn], 0, 0, 0);
      __builtin_amdgcn_s_setprio(0);
    }
  }

  // epilogue: row = m0 + wm*128 + fm*16 + ko*4 + j; col = n0 + wn*64 + fn*16 + la
  const int crow0 = m0 + wm * 128;
  const int ccol0 = n0 + wn * 64;
#pragma unroll
  for (int fn = 0; fn < 4; ++fn) {
    int c = ccol0 + fn * 16 + la;
    float bv = bias[c];
#pragma unroll
    for (int fm = 0; fm < 8; ++fm)
#pragma unroll
      for (int j = 0; j < 4; ++j) {
        int rr = crow0 + fm * 16 + (ko << 2) + j;
        float v = acc[fm][fn][j] + bv;
        if (RELU) v = fmaxf(v, 0.0f);
        if (BF16OUT) ((unsigned short*)Cv)[(size_t)rr * N + c] = f2bf(v);
        else         ((float*)Cv)[(size_t)rr * N + c] = v;
      }
  }
}

// ---------------- round-5 GEMM (L2 / grouped experts) ----------------
template <int TBM, int TBN, int WM, int WN,
          bool RELU, bool BF16OUT, bool GROUPED, bool SCATTER, bool GATHER>
__global__ __launch_bounds__(256) void k_gemm(
    const unsigned short* __restrict__ A,
    const unsigned short* __restrict__ WT,
    const float* __restrict__ bias,
    void* __restrict__ Cv,
    int M, int N, int K,
    const int* __restrict__ starts, const int* __restrict__ counts,
    const int* __restrict__ perm) {
  constexpr int FM = TBM / WM / 16;
  constexpr int FN = TBN / WN / 16;
  constexpr int ALOADS = TBM / 64;
  constexpr int BLOADS = TBN / 64;
  constexpr int LDS_LD = ALOADS + BLOADS;

  const int nby = gridDim.y;
  const int nwg = gridDim.x * nby;
  int orig = blockIdx.x + gridDim.x * blockIdx.y;
  int q = nwg >> 3, r = nwg & 7;
  int xcd = orig & 7, idx = orig >> 3;
  int wg = (xcd < r ? xcd * (q + 1) : r * (q + 1) + (xcd - r) * q) + idx;
  int bx = wg / nby, by = wg % nby;

  int Meff, start = 0, mo;
  const unsigned short* Wp = WT;
  const float* biasp = bias;
  if (GROUPED) {
    int bxr = bx;
    int found = 0;
#pragma unroll
    for (int e = 0; e < N_CLS; ++e) {
      int c = counts[e];
      int nb = (c + TBM - 1) / TBM;
      if (!found && bxr < nb) {
        found = 1; Meff = c; start = starts[e]; mo = bxr * TBM;
        Wp = WT + (size_t)e * N * K; biasp = bias + (size_t)e * N;
      }
      if (!found) bxr -= nb;
    }
    if (!found) return;
    if (!GATHER) A += (size_t)start * K;
  } else {
    Meff = M; mo = bx * TBM;
  }
  const int n0 = by * TBN;

  __shared__ __align__(16) unsigned short As[3][TBM * 32];
  __shared__ __align__(16) unsigned short Bs[3][TBN * 32];

  const int t = threadIdx.x;
  const int l = t & 63;
  const int w = t >> 6;
  const int wm = (w / WN) * (TBM / WM);
  const int wn = (w % WN) * (TBN / WN);

  const int srow = t >> 2;
  const int scol = (t & 3) * 8;
  const unsigned short* ag[ALOADS];
  const unsigned short* bg[BLOADS];
#pragma unroll
  for (int i = 0; i < ALOADS; ++i) {
    int arow = mo + srow + i * 64;
    if (GROUPED) arow = arow < Meff ? arow : Meff - 1;
    int srcrow = GATHER ? perm[start + arow] : arow;
    ag[i] = A + (size_t)srcrow * K + scol;
  }
#pragma unroll
  for (int i = 0; i < BLOADS; ++i)
    bg[i] = Wp + (size_t)(n0 + srow + i * 64) * K + scol;

  auto STAGE = [&](int buf) {
#pragma unroll
    for (int i = 0; i < ALOADS; ++i) {
      gload16(ag[i], &As[buf][t * 8 + i * 2048]);
      ag[i] += 32;
    }
#pragma unroll
    for (int i = 0; i < BLOADS; ++i) {
      gload16(bg[i], &Bs[buf][t * 8 + i * 2048]);
      bg[i] += 32;
    }
  };

  f32x4 acc[FM][FN] = {};

  const int nt = K / 32;
  STAGE(0);
  STAGE(1);
  for (int tI = 0; tI < nt; ++tI) {
    if (tI + 1 < nt)
      asm volatile("s_waitcnt vmcnt(%0)" :: "i"(LDS_LD) : "memory");
    else
      asm volatile("s_waitcnt vmcnt(0)" ::: "memory");
    __builtin_amdgcn_s_barrier();
    __builtin_amdgcn_sched_barrier(0);
    if (tI + 2 < nt) STAGE((tI + 2) % 3);

    const int cur = tI % 3;
    bf16x8 af[FM], bfr[FN];
#pragma unroll
    for (int i = 0; i < FM; ++i)
      af[i] = *(const bf16x8*)(&As[cur][(wm + i * 16 + (l & 15)) * 32 + (l >> 4) * 8]);
#pragma unroll
    for (int i = 0; i < FN; ++i)
      bfr[i] = *(const bf16x8*)(&Bs[cur][(wn + i * 16 + (l & 15)) * 32 + (l >> 4) * 8]);
#pragma unroll
    for (int mi = 0; mi < FM; ++mi)
#pragma unroll
      for (int ni = 0; ni < FN; ++ni)
        acc[mi][ni] = __builtin_amdgcn_mfma_f32_16x16x32_bf16(af[mi], bfr[ni], acc[mi][ni], 0, 0, 0);
  }

  const int cb = n0 + wn + (l & 15);
#pragma unroll
  for (int ni = 0; ni < FN; ++ni) {
    int c = cb + ni * 16;
    float bv = biasp[c];
#pragma unroll
    for (int mi = 0; mi < FM; ++mi) {
#pragma unroll
      for (int j = 0; j < 4; ++j) {
        int rl2 = wm + mi * 16 + ((l >> 4) << 2) + j;
        int re = mo + rl2;
        if (GROUPED && re >= Meff) continue;
        float v = acc[mi][ni][j] + bv;
        if (RELU) v = fmaxf(v, 0.0f);
        int orow;
        if (SCATTER)      orow = perm[start + re];
        else if (GROUPED) orow = start + re;
        else              orow = re;
        if (BF16OUT) ((unsigned short*)Cv)[(size_t)orow * N + c] = f2bf(v);
        else         ((float*)Cv)[(size_t)orow * N + c] = v;
      }
    }
  }
}

#define GX_GROUPED 74   // worst-case sum of ceil(counts[e]/128) over 10 experts

// ---------------- launch ----------------
extern "C" void kernel_launch(void* const* d_in, const int* in_sizes, int n_in,
                              void* d_out, int out_size, void* d_ws, size_t ws_size,
                              hipStream_t stream) {
  const float* x      = (const float*)d_in[0];
  const int*   labels = (const int*)d_in[1];
  const float* W1  = (const float*)d_in[2];  const float* b1  = (const float*)d_in[3];
  const float* W2  = (const float*)d_in[4];  const float* b2  = (const float*)d_in[5];
  const float* EW1 = (const float*)d_in[6];  const float* Eb1 = (const float*)d_in[7];
  const float* EW2 = (const float*)d_in[8];  const float* Eb2 = (const float*)d_in[9];
  const float* DW1 = (const float*)d_in[10]; const float* Db1 = (const float*)d_in[11];
  const float* DW2 = (const float*)d_in[12]; const float* Db2 = (const float*)d_in[13];
  float* out = (float*)d_out;

  char* ws = (char*)d_ws;
  size_t o = 0;
  unsigned short* W1T  = (unsigned short*)(ws + o); o += (size_t)D_IN * D_H * 2;
  unsigned short* W2T  = (unsigned short*)(ws + o); o += (size_t)D_H * D_BOT * 2;
  unsigned short* EW1T = (unsigned short*)(ws + o); o += (size_t)N_CLS * D_BOT * D_EXP * 2;
  unsigned short* EW2T = (unsigned short*)(ws + o); o += (size_t)N_CLS * D_EXP * D_BOT * 2;
  unsigned short* DW1T = (unsigned short*)(ws + o); o += (size_t)D_BOT * D_H * 2;
  unsigned short* DW2T = (unsigned short*)(ws + o); o += (size_t)D_H * D_IN * 2;
  unsigned short* xb   = (unsigned short*)(ws + o); o += (size_t)Bsz * D_IN * 2;
  unsigned short* e1p  = xb;                         // alias: xb dead after L1
  unsigned short* actA = (unsigned short*)(ws + o); o += (size_t)Bsz * D_H * 2;
  unsigned short* h2   = (unsigned short*)(ws + o); o += (size_t)Bsz * D_BOT * 2;
  unsigned short* sel  = (unsigned short*)(ws + o); o += (size_t)Bsz * D_BOT * 2;
  int* counts = (int*)(ws + o);
  int* starts = counts + 16;
  int* perm   = counts + 64;

  // routing metadata (single block)
  k_route<<<1, 1024, 0, stream>>>(labels, counts, starts, perm);

  // conversions
  k_cvt<<<(Bsz * D_IN) / (256 * 8), 256, 0, stream>>>(x, xb);
  k_transpose_cvt<<<dim3(D_H / 32, D_IN / 32, 1),  dim3(32, 8), 0, stream>>>(W1, W1T, D_IN, D_H);
  k_transpose_cvt<<<dim3(D_BOT / 32, D_H / 32, 1), dim3(32, 8), 0, stream>>>(W2, W2T, D_H, D_BOT);
  k_transpose_cvt<<<dim3(D_EXP / 32, D_BOT / 32, N_CLS), dim3(32, 8), 0, stream>>>(EW1, EW1T, D_BOT, D_EXP);
  k_transpose_cvt<<<dim3(D_BOT / 32, D_EXP / 32, N_CLS), dim3(32, 8), 0, stream>>>(EW2, EW2T, D_EXP, D_BOT);
  k_transpose_cvt<<<dim3(D_H / 32, D_BOT / 32, 1), dim3(32, 8), 0, stream>>>(DW1, DW1T, D_BOT, D_H);
  k_transpose_cvt<<<dim3(D_IN / 32, D_H / 32, 1),  dim3(32, 8), 0, stream>>>(DW2, DW2T, D_H, D_IN);

  // encoder
  k_gemm8<true, true><<<dim3(Bsz / 256, D_H / 256), 512, 0, stream>>>(
      xb, W1T, b1, actA, Bsz, D_H, D_IN);
  k_gemm<256, 64, 4, 1, true, true, false, false, false><<<dim3(Bsz / 256, D_BOT / 64), 256, 0, stream>>>(
      actA, W2T, b2, h2, Bsz, D_BOT, D_H, nullptr, nullptr, nullptr);

  // routed experts; E1 gathers A rows via perm during staging, E2 scatters back
  k_gemm<128, 128, 2, 2, true, true, true, false, true><<<dim3(GX_GROUPED, D_EXP / 128), 256, 0, stream>>>(
      h2, EW1T, Eb1, e1p, Bsz, D_EXP, D_BOT, starts, counts, perm);
  k_gemm<128, 64, 4, 1, true, true, true, true, false><<<dim3(GX_GROUPED, D_BOT / 64), 256, 0, stream>>>(
      e1p, EW2T, Eb2, sel, Bsz, D_BOT, D_EXP, starts, counts, perm);

  // decoder
  k_gemm8<true, true><<<dim3(Bsz / 256, D_H / 256), 512, 0, stream>>>(
      sel, DW1T, Db1, actA, Bsz, D_H, D_BOT);
  k_gemm8<false, false><<<dim3(Bsz / 256, D_IN / 256), 512, 0, stream>>>(
      actA, DW2T, Db2, out, Bsz, D_IN, D_H);
}

// Round 10
// 244.088 us; speedup vs baseline: 1.1612x; 1.1612x over previous
//
#include <hip/hip_runtime.h>
#include <hip/hip_bf16.h>
#include <stdint.h>

// ---------------- types / helpers ----------------
typedef __attribute__((ext_vector_type(8))) short bf16x8;   // 8 bf16 = 4 VGPRs
typedef __attribute__((ext_vector_type(4))) float f32x4;

__device__ __forceinline__ unsigned short f2bf(float f) {
  unsigned int u = __float_as_uint(f);
  u += 0x7fff + ((u >> 16) & 1);   // round-to-nearest-even
  return (unsigned short)(u >> 16);
}

__device__ __forceinline__ void gload16(const void* g, void* l) {
  __builtin_amdgcn_global_load_lds(
      (const __attribute__((address_space(1))) void*)g,
      (__attribute__((address_space(3))) void*)l, 16, 0, 0);
}

// ---------------- problem constants ----------------
#define Bsz   8192
#define D_IN  1024
#define D_H   2048
#define D_BOT 512
#define D_EXP 1024
#define N_CLS 10

// ---------------- routing: hist + scan + assign in ONE block ----------------
__global__ __launch_bounds__(1024) void k_route(const int* __restrict__ lab,
                                                int* __restrict__ counts,
                                                int* __restrict__ starts,
                                                int* __restrict__ perm) {
  __shared__ int scnt[N_CLS], scur[N_CLS];
  const int t = threadIdx.x;
  if (t < N_CLS) scnt[t] = 0;
  __syncthreads();
  int myl[8];
#pragma unroll
  for (int i = 0; i < 8; ++i) {
    myl[i] = lab[t * 8 + i];
    atomicAdd(&scnt[myl[i]], 1);
  }
  __syncthreads();
  if (t == 0) {
    int s = 0;
    for (int e = 0; e < N_CLS; ++e) {
      starts[e] = s; scur[e] = s; counts[e] = scnt[e]; s += scnt[e];
    }
  }
  __syncthreads();
#pragma unroll
  for (int i = 0; i < 8; ++i) {
    int p = atomicAdd(&scur[myl[i]], 1);
    perm[p] = t * 8 + i;
  }
}

// ---------------- fused weight prep: ALL transposes in one launch ----------------
// Each block: one 32x32 fp32 tile of some W [K][N] -> bf16 WT [N][K].
// Segment table (compile-time): cumulative block counts.
__global__ void k_prep(const float* __restrict__ W1,  const float* __restrict__ W2,
                       const float* __restrict__ EW1, const float* __restrict__ EW2,
                       const float* __restrict__ DW1, const float* __restrict__ DW2,
                       unsigned short* __restrict__ W1T,  unsigned short* __restrict__ W2T,
                       unsigned short* __restrict__ EW1T, unsigned short* __restrict__ EW2T,
                       unsigned short* __restrict__ DW1T, unsigned short* __restrict__ DW2T) {
  const int bid = blockIdx.x;
  const float* in; unsigned short* out; int K, N, tile;
  if (bid < 2048)        { in = W1;  out = W1T;  K = D_IN;  N = D_H;   tile = bid; }
  else if (bid < 3072)   { in = W2;  out = W2T;  K = D_H;   N = D_BOT; tile = bid - 2048; }
  else if (bid < 8192)   { int r = bid - 3072; int e = r >> 9; tile = r & 511;
                           K = D_BOT; N = D_EXP;
                           in = EW1 + (size_t)e * K * N; out = EW1T + (size_t)e * K * N; }
  else if (bid < 13312)  { int r = bid - 8192; int e = r >> 9; tile = r & 511;
                           K = D_EXP; N = D_BOT;
                           in = EW2 + (size_t)e * K * N; out = EW2T + (size_t)e * K * N; }
  else if (bid < 14336)  { in = DW1; out = DW1T; K = D_BOT; N = D_H;   tile = bid - 13312; }
  else                   { in = DW2; out = DW2T; K = D_H;   N = D_IN;  tile = bid - 14336; }
  const int ntx = N >> 5;
  const int n0 = (tile % ntx) * 32, k0 = (tile / ntx) * 32;

  __shared__ float tl[32][33];
  const int tx = threadIdx.x, ty = threadIdx.y;   // 32 x 8
#pragma unroll
  for (int i = 0; i < 4; ++i) {
    int k = ty + i * 8;
    tl[k][tx] = in[(size_t)(k0 + k) * N + n0 + tx];
  }
  __syncthreads();
#pragma unroll
  for (int i = 0; i < 4; ++i) {
    int n = ty + i * 8;
    out[(size_t)(n0 + n) * K + k0 + tx] = f2bf(tl[tx][n]);
  }
}

// ============ R6 4-phase GEMM (restored): C = act(A * WT^T + b) ============
// BK=64, 8 waves (2M x 4N), per-wave (BM/2 x 64). 4 phases per K-tile (one
// 32-col x QR-row quadrant each); double-buffered XOR-16B-swizzled LDS
// (bank-conflict-free, verified R6); stage-all for kt+1 at phase 0;
// vmcnt(0)+barrier once per K-tile; setprio on MFMA clusters.
// AFP32: A is fp32; staging reg-loads float4 pairs, converts to bf16, ds_writes
// (fuses the x->bf16 conversion into L1; lgkmcnt(0) added at the publishing wait).
template <int BM, int BN, bool RELU, bool BF16OUT, bool AFP32>
__global__ __launch_bounds__(512, 2) void k_gemm8(
    const void* __restrict__ Av,            // [M][K] bf16 (or fp32 if AFP32)
    const unsigned short* __restrict__ WT,  // [N][K] bf16
    const float* __restrict__ bias,         // [N] fp32
    void* __restrict__ Cv,                  // [M][N] bf16 or fp32
    int M, int N, int K) {
  constexpr int WROWS = BM / 2;    // per-wave rows
  constexpr int QR = WROWS / 2;    // quadrant rows
  constexpr int FMq = QR / 16;     // m-frags per quadrant
  constexpr int ACH = BM / 64;     // 8KB stage chunks per K-tile
  constexpr int BCH = BN / 64;

  // XCD-bijective chunk swizzle, y-fastest work order
  const int nby = gridDim.y;
  const int nwg = gridDim.x * nby;
  int orig = blockIdx.x + gridDim.x * blockIdx.y;
  int q = nwg >> 3, r = nwg & 7;
  int xcd = orig & 7, idx = orig >> 3;
  int wg = (xcd < r ? xcd * (q + 1) : r * (q + 1) + (xcd - r) * q) + idx;
  int bx = wg / nby, by = wg % nby;
  const int m0 = bx * BM, n0 = by * BN;

  __shared__ __align__(16) unsigned short As[2][BM * 64];
  __shared__ __align__(16) unsigned short Bs[2][BN * 64];

  const int t = threadIdx.x;
  const int l = t & 63;
  const int w = t >> 6;
  const int wm = w >> 2, wn = w & 3;   // 2M x 4N waves

  // staging coords: thread t covers 16B of each 8KB chunk (64 rows x 128B)
  const int rl = t >> 3;                 // row within chunk
  const int sl16 = (t & 7) ^ (rl & 7);   // inverse-swizzled 16B slot
  const unsigned short* a16[ACH];
  const float* a32[ACH];
  const unsigned short* bsrc[BCH];
#pragma unroll
  for (int i = 0; i < ACH; ++i) {
    if constexpr (AFP32)
      a32[i] = (const float*)Av + (size_t)(m0 + i * 64 + rl) * K + sl16 * 8;
    else
      a16[i] = (const unsigned short*)Av + (size_t)(m0 + i * 64 + rl) * K + sl16 * 8;
  }
#pragma unroll
  for (int i = 0; i < BCH; ++i)
    bsrc[i] = WT + (size_t)(n0 + i * 64 + rl) * K + sl16 * 8;
  const int dst = t * 8;

  auto STAGE = [&](int kt, int buf) {
    if constexpr (AFP32) {
#pragma unroll
      for (int i = 0; i < ACH; ++i) {
        const float* s = a32[i] + kt * 64;
        float4 lo = *(const float4*)s;
        float4 hi = *(const float4*)(s + 4);
        uint4 o;
        o.x = (unsigned)f2bf(lo.x) | ((unsigned)f2bf(lo.y) << 16);
        o.y = (unsigned)f2bf(lo.z) | ((unsigned)f2bf(lo.w) << 16);
        o.z = (unsigned)f2bf(hi.x) | ((unsigned)f2bf(hi.y) << 16);
        o.w = (unsigned)f2bf(hi.z) | ((unsigned)f2bf(hi.w) << 16);
        *(uint4*)(&As[buf][i * 4096 + dst]) = o;
      }
    } else {
#pragma unroll
      for (int i = 0; i < ACH; ++i)
        gload16(a16[i] + kt * 64, &As[buf][i * 4096 + dst]);
    }
#pragma unroll
    for (int i = 0; i < BCH; ++i)
      gload16(bsrc[i] + kt * 64, &Bs[buf][i * 4096 + dst]);
  };

  f32x4 acc[2][2][FMq][2] = {};   // [qm][qn][fm][fn]
  bf16x8 af[FMq][2];              // current qm's A frags [fm][ks]
  bf16x8 bq[2][2][2];             // both qn's B frags [qn][fn][ks]

  const int la = l & 15;
  const int ko = l >> 4;          // 0..3
  const int arow0 = wm * WROWS + la;
  const int brow0 = wn * 64 + la;

  const int nt = K / 64;
  STAGE(0, 0);

  for (int kt = 0; kt < nt; ++kt) {
    const int cur = kt & 1;
    const char* Ab = (const char*)As[cur];
    const char* Bb = (const char*)Bs[cur];

    if constexpr (AFP32)
      asm volatile("s_waitcnt vmcnt(0) lgkmcnt(0)" ::: "memory");
    else
      asm volatile("s_waitcnt vmcnt(0)" ::: "memory");
    __builtin_amdgcn_s_barrier();
    if (kt + 1 < nt) STAGE(kt + 1, cur ^ 1);
    __builtin_amdgcn_sched_barrier(0);

    // ---- phase 0: read A(q0)+B(q0); MFMA q(0,0) ----
#pragma unroll
    for (int fm = 0; fm < FMq; ++fm)
#pragma unroll
      for (int ks = 0; ks < 2; ++ks) {
        int row = arow0 + fm * 16;
        int s = ks * 4 + ko;
        af[fm][ks] = *(const bf16x8*)(Ab + (row << 7) + ((s ^ (row & 7)) << 4));
      }
#pragma unroll
    for (int fn = 0; fn < 2; ++fn)
#pragma unroll
      for (int ks = 0; ks < 2; ++ks) {
        int row = brow0 + fn * 16;
        int s = ks * 4 + ko;
        bq[0][fn][ks] = *(const bf16x8*)(Bb + (row << 7) + ((s ^ (row & 7)) << 4));
      }
    __builtin_amdgcn_s_setprio(1);
#pragma unroll
    for (int fm = 0; fm < FMq; ++fm)
#pragma unroll
      for (int fn = 0; fn < 2; ++fn)
#pragma unroll
        for (int ks = 0; ks < 2; ++ks)
          acc[0][0][fm][fn] = __builtin_amdgcn_mfma_f32_16x16x32_bf16(
              af[fm][ks], bq[0][fn][ks], acc[0][0][fm][fn], 0, 0, 0);
    __builtin_amdgcn_s_setprio(0);
    __builtin_amdgcn_s_barrier();

    // ---- phase 1: read B(q1); MFMA q(0,1) ----
#pragma unroll
    for (int fn = 0; fn < 2; ++fn)
#pragma unroll
      for (int ks = 0; ks < 2; ++ks) {
        int row = brow0 + 32 + fn * 16;
        int s = ks * 4 + ko;
        bq[1][fn][ks] = *(const bf16x8*)(Bb + (row << 7) + ((s ^ (row & 7)) << 4));
      }
    __builtin_amdgcn_s_setprio(1);
#pragma unroll
    for (int fm = 0; fm < FMq; ++fm)
#pragma unroll
      for (int fn = 0; fn < 2; ++fn)
#pragma unroll
        for (int ks = 0; ks < 2; ++ks)
          acc[0][1][fm][fn] = __builtin_amdgcn_mfma_f32_16x16x32_bf16(
              af[fm][ks], bq[1][fn][ks], acc[0][1][fm][fn], 0, 0, 0);
    __builtin_amdgcn_s_setprio(0);
    __builtin_amdgcn_s_barrier();

    // ---- phase 2: read A(q1); MFMA q(1,0) ----
#pragma unroll
    for (int fm = 0; fm < FMq; ++fm)
#pragma unroll
      for (int ks = 0; ks < 2; ++ks) {
        int row = arow0 + QR + fm * 16;
        int s = ks * 4 + ko;
        af[fm][ks] = *(const bf16x8*)(Ab + (row << 7) + ((s ^ (row & 7)) << 4));
      }
    __builtin_amdgcn_s_setprio(1);
#pragma unroll
    for (int fm = 0; fm < FMq; ++fm)
#pragma unroll
      for (int fn = 0; fn < 2; ++fn)
#pragma unroll
        for (int ks = 0; ks < 2; ++ks)
          acc[1][0][fm][fn] = __builtin_amdgcn_mfma_f32_16x16x32_bf16(
              af[fm][ks], bq[0][fn][ks], acc[1][0][fm][fn], 0, 0, 0);
    __builtin_amdgcn_s_setprio(0);
    __builtin_amdgcn_s_barrier();

    // ---- phase 3: MFMA q(1,1) ----
    __builtin_amdgcn_s_setprio(1);
#pragma unroll
    for (int fm = 0; fm < FMq; ++fm)
#pragma unroll
      for (int fn = 0; fn < 2; ++fn)
#pragma unroll
        for (int ks = 0; ks < 2; ++ks)
          acc[1][1][fm][fn] = __builtin_amdgcn_mfma_f32_16x16x32_bf16(
              af[fm][ks], bq[1][fn][ks], acc[1][1][fm][fn], 0, 0, 0);
    __builtin_amdgcn_s_setprio(0);
  }
  asm volatile("s_waitcnt vmcnt(0)" ::: "memory");

  // epilogue: row = qm*QR + fm*16 + ko*4 + j, col = qn*32 + fn*16 + la
  const int crow0 = m0 + wm * WROWS;
  const int ccol0 = n0 + wn * 64;
#pragma unroll
  for (int qn = 0; qn < 2; ++qn)
#pragma unroll
    for (int fn = 0; fn < 2; ++fn) {
      int c = ccol0 + qn * 32 + fn * 16 + la;
      float bv = bias[c];
#pragma unroll
      for (int qm = 0; qm < 2; ++qm)
#pragma unroll
        for (int fm = 0; fm < FMq; ++fm)
#pragma unroll
          for (int j = 0; j < 4; ++j) {
            int rr = crow0 + qm * QR + fm * 16 + (ko << 2) + j;
            float v = acc[qm][qn][fm][fn][j] + bv;
            if (RELU) v = fmaxf(v, 0.0f);
            if (BF16OUT) ((unsigned short*)Cv)[(size_t)rr * N + c] = f2bf(v);
            else         ((float*)Cv)[(size_t)rr * N + c] = v;
          }
    }
}

// ---------------- round-5 GEMM (L2 / grouped experts) ----------------
template <int TBM, int TBN, int WM, int WN,
          bool RELU, bool BF16OUT, bool GROUPED, bool SCATTER, bool GATHER>
__global__ __launch_bounds__(256) void k_gemm(
    const unsigned short* __restrict__ A,
    const unsigned short* __restrict__ WT,
    const float* __restrict__ bias,
    void* __restrict__ Cv,
    int M, int N, int K,
    const int* __restrict__ starts, const int* __restrict__ counts,
    const int* __restrict__ perm) {
  constexpr int FM = TBM / WM / 16;
  constexpr int FN = TBN / WN / 16;
  constexpr int ALOADS = TBM / 64;
  constexpr int BLOADS = TBN / 64;
  constexpr int LDS_LD = ALOADS + BLOADS;

  const int nby = gridDim.y;
  const int nwg = gridDim.x * nby;
  int orig = blockIdx.x + gridDim.x * blockIdx.y;
  int q = nwg >> 3, r = nwg & 7;
  int xcd = orig & 7, idx = orig >> 3;
  int wg = (xcd < r ? xcd * (q + 1) : r * (q + 1) + (xcd - r) * q) + idx;
  int bx = wg / nby, by = wg % nby;

  int Meff, start = 0, mo;
  const unsigned short* Wp = WT;
  const float* biasp = bias;
  if (GROUPED) {
    int bxr = bx;
    int found = 0;
#pragma unroll
    for (int e = 0; e < N_CLS; ++e) {
      int c = counts[e];
      int nb = (c + TBM - 1) / TBM;
      if (!found && bxr < nb) {
        found = 1; Meff = c; start = starts[e]; mo = bxr * TBM;
        Wp = WT + (size_t)e * N * K; biasp = bias + (size_t)e * N;
      }
      if (!found) bxr -= nb;
    }
    if (!found) return;
    if (!GATHER) A += (size_t)start * K;
  } else {
    Meff = M; mo = bx * TBM;
  }
  const int n0 = by * TBN;

  __shared__ __align__(16) unsigned short As[3][TBM * 32];
  __shared__ __align__(16) unsigned short Bs[3][TBN * 32];

  const int t = threadIdx.x;
  const int l = t & 63;
  const int w = t >> 6;
  const int wm = (w / WN) * (TBM / WM);
  const int wn = (w % WN) * (TBN / WN);

  const int srow = t >> 2;
  const int scol = (t & 3) * 8;
  const unsigned short* ag[ALOADS];
  const unsigned short* bg[BLOADS];
#pragma unroll
  for (int i = 0; i < ALOADS; ++i) {
    int arow = mo + srow + i * 64;
    if (GROUPED) arow = arow < Meff ? arow : Meff - 1;
    int srcrow = GATHER ? perm[start + arow] : arow;
    ag[i] = A + (size_t)srcrow * K + scol;
  }
#pragma unroll
  for (int i = 0; i < BLOADS; ++i)
    bg[i] = Wp + (size_t)(n0 + srow + i * 64) * K + scol;

  auto STAGE = [&](int buf) {
#pragma unroll
    for (int i = 0; i < ALOADS; ++i) {
      gload16(ag[i], &As[buf][t * 8 + i * 2048]);
      ag[i] += 32;
    }
#pragma unroll
    for (int i = 0; i < BLOADS; ++i) {
      gload16(bg[i], &Bs[buf][t * 8 + i * 2048]);
      bg[i] += 32;
    }
  };

  f32x4 acc[FM][FN] = {};

  const int nt = K / 32;
  STAGE(0);
  STAGE(1);
  for (int tI = 0; tI < nt; ++tI) {
    if (tI + 1 < nt)
      asm volatile("s_waitcnt vmcnt(%0)" :: "i"(LDS_LD) : "memory");
    else
      asm volatile("s_waitcnt vmcnt(0)" ::: "memory");
    __builtin_amdgcn_s_barrier();
    __builtin_amdgcn_sched_barrier(0);
    if (tI + 2 < nt) STAGE((tI + 2) % 3);

    const int cur = tI % 3;
    bf16x8 af[FM], bfr[FN];
#pragma unroll
    for (int i = 0; i < FM; ++i)
      af[i] = *(const bf16x8*)(&As[cur][(wm + i * 16 + (l & 15)) * 32 + (l >> 4) * 8]);
#pragma unroll
    for (int i = 0; i < FN; ++i)
      bfr[i] = *(const bf16x8*)(&Bs[cur][(wn + i * 16 + (l & 15)) * 32 + (l >> 4) * 8]);
#pragma unroll
    for (int mi = 0; mi < FM; ++mi)
#pragma unroll
      for (int ni = 0; ni < FN; ++ni)
        acc[mi][ni] = __builtin_amdgcn_mfma_f32_16x16x32_bf16(af[mi], bfr[ni], acc[mi][ni], 0, 0, 0);
  }

  const int cb = n0 + wn + (l & 15);
#pragma unroll
  for (int ni = 0; ni < FN; ++ni) {
    int c = cb + ni * 16;
    float bv = biasp[c];
#pragma unroll
    for (int mi = 0; mi < FM; ++mi) {
#pragma unroll
      for (int j = 0; j < 4; ++j) {
        int rl2 = wm + mi * 16 + ((l >> 4) << 2) + j;
        int re = mo + rl2;
        if (GROUPED && re >= Meff) continue;
        float v = acc[mi][ni][j] + bv;
        if (RELU) v = fmaxf(v, 0.0f);
        int orow;
        if (SCATTER)      orow = perm[start + re];
        else if (GROUPED) orow = start + re;
        else              orow = re;
        if (BF16OUT) ((unsigned short*)Cv)[(size_t)orow * N + c] = f2bf(v);
        else         ((float*)Cv)[(size_t)orow * N + c] = v;
      }
    }
  }
}

#define GX_GROUPED 74   // worst-case sum of ceil(counts[e]/128) over 10 experts

// ---------------- launch ----------------
extern "C" void kernel_launch(void* const* d_in, const int* in_sizes, int n_in,
                              void* d_out, int out_size, void* d_ws, size_t ws_size,
                              hipStream_t stream) {
  const float* x      = (const float*)d_in[0];
  const int*   labels = (const int*)d_in[1];
  const float* W1  = (const float*)d_in[2];  const float* b1  = (const float*)d_in[3];
  const float* W2  = (const float*)d_in[4];  const float* b2  = (const float*)d_in[5];
  const float* EW1 = (const float*)d_in[6];  const float* Eb1 = (const float*)d_in[7];
  const float* EW2 = (const float*)d_in[8];  const float* Eb2 = (const float*)d_in[9];
  const float* DW1 = (const float*)d_in[10]; const float* Db1 = (const float*)d_in[11];
  const float* DW2 = (const float*)d_in[12]; const float* Db2 = (const float*)d_in[13];
  float* out = (float*)d_out;

  char* ws = (char*)d_ws;
  size_t o = 0;
  unsigned short* W1T  = (unsigned short*)(ws + o); o += (size_t)D_IN * D_H * 2;
  unsigned short* W2T  = (unsigned short*)(ws + o); o += (size_t)D_H * D_BOT * 2;
  unsigned short* EW1T = (unsigned short*)(ws + o); o += (size_t)N_CLS * D_BOT * D_EXP * 2;
  unsigned short* EW2T = (unsigned short*)(ws + o); o += (size_t)N_CLS * D_EXP * D_BOT * 2;
  unsigned short* DW1T = (unsigned short*)(ws + o); o += (size_t)D_BOT * D_H * 2;
  unsigned short* DW2T = (unsigned short*)(ws + o); o += (size_t)D_H * D_IN * 2;
  unsigned short* e1p  = (unsigned short*)(ws + o); o += (size_t)Bsz * D_EXP * 2;
  unsigned short* actA = (unsigned short*)(ws + o); o += (size_t)Bsz * D_H * 2;
  unsigned short* h2   = (unsigned short*)(ws + o); o += (size_t)Bsz * D_BOT * 2;
  unsigned short* sel  = (unsigned short*)(ws + o); o += (size_t)Bsz * D_BOT * 2;
  int* counts = (int*)(ws + o);
  int* starts = counts + 16;
  int* perm   = counts + 64;

  // routing metadata (single block)
  k_route<<<1, 1024, 0, stream>>>(labels, counts, starts, perm);

  // all weight transposes in ONE launch
  k_prep<<<16384, dim3(32, 8), 0, stream>>>(W1, W2, EW1, EW2, DW1, DW2,
                                            W1T, W2T, EW1T, EW2T, DW1T, DW2T);

  // encoder (L1 reads x fp32 directly; conversion fused into A-staging)
  k_gemm8<256, 256, true, true, true><<<dim3(Bsz / 256, D_H / 256), 512, 0, stream>>>(
      x, W1T, b1, actA, Bsz, D_H, D_IN);
  k_gemm<128, 64, 4, 1, true, true, false, false, false><<<dim3(Bsz / 128, D_BOT / 64), 256, 0, stream>>>(
      actA, W2T, b2, h2, Bsz, D_BOT, D_H, nullptr, nullptr, nullptr);

  // routed experts; E1 gathers A rows via perm during staging, E2 scatters back
  k_gemm<128, 128, 2, 2, true, true, true, false, true><<<dim3(GX_GROUPED, D_EXP / 128), 256, 0, stream>>>(
      h2, EW1T, Eb1, e1p, Bsz, D_EXP, D_BOT, starts, counts, perm);
  k_gemm<128, 64, 4, 1, true, true, true, true, false><<<dim3(GX_GROUPED, D_BOT / 64), 256, 0, stream>>>(
      e1p, EW2T, Eb2, sel, Bsz, D_BOT, D_EXP, starts, counts, perm);

  // decoder
  k_gemm8<256, 256, true, true, false><<<dim3(Bsz / 256, D_H / 256), 512, 0, stream>>>(
      sel, DW1T, Db1, actA, Bsz, D_H, D_BOT);
  k_gemm8<128, 256, false, false, false><<<dim3(Bsz / 128, D_IN / 256), 512, 0, stream>>>(
      actA, DW2T, Db2, out, Bsz, D_IN, D_H);
}

// Round 12
// 243.494 us; speedup vs baseline: 1.1640x; 1.0024x over previous
//
#include <hip/hip_runtime.h>
#include <hip/hip_bf16.h>
#include <stdint.h>

// ---------------- types / helpers ----------------
typedef __attribute__((ext_vector_type(8))) short bf16x8;   // 8 bf16 = 4 VGPRs
typedef __attribute__((ext_vector_type(4))) float f32x4;

__device__ __forceinline__ unsigned short f2bf(float f) {
  unsigned int u = __float_as_uint(f);
  u += 0x7fff + ((u >> 16) & 1);   // round-to-nearest-even
  return (unsigned short)(u >> 16);
}

__device__ __forceinline__ void gload16(const void* g, void* l) {
  __builtin_amdgcn_global_load_lds(
      (const __attribute__((address_space(1))) void*)g,
      (__attribute__((address_space(3))) void*)l, 16, 0, 0);
}

// ---------------- problem constants ----------------
#define Bsz   8192
#define D_IN  1024
#define D_H   2048
#define D_BOT 512
#define D_EXP 1024
#define N_CLS 10

// ---------------- routing: hist + scan + assign in ONE block ----------------
__global__ __launch_bounds__(1024) void k_route(const int* __restrict__ lab,
                                                int* __restrict__ counts,
                                                int* __restrict__ starts,
                                                int* __restrict__ perm) {
  __shared__ int scnt[N_CLS], scur[N_CLS];
  const int t = threadIdx.x;
  if (t < N_CLS) scnt[t] = 0;
  __syncthreads();
  int myl[8];
#pragma unroll
  for (int i = 0; i < 8; ++i) {
    myl[i] = lab[t * 8 + i];
    atomicAdd(&scnt[myl[i]], 1);
  }
  __syncthreads();
  if (t == 0) {
    int s = 0;
    for (int e = 0; e < N_CLS; ++e) {
      starts[e] = s; scur[e] = s; counts[e] = scnt[e]; s += scnt[e];
    }
  }
  __syncthreads();
#pragma unroll
  for (int i = 0; i < 8; ++i) {
    int p = atomicAdd(&scur[myl[i]], 1);
    perm[p] = t * 8 + i;
  }
}

// fp32 -> bf16 elementwise (8 elems/thread)
__global__ void k_cvt(const float* __restrict__ in, unsigned short* __restrict__ out) {
  int i = (blockIdx.x * blockDim.x + threadIdx.x) * 8;
  const float4* p = (const float4*)(in + i);
  float4 a = p[0], b = p[1];
  uint4 o;
  o.x = (unsigned)f2bf(a.x) | ((unsigned)f2bf(a.y) << 16);
  o.y = (unsigned)f2bf(a.z) | ((unsigned)f2bf(a.w) << 16);
  o.z = (unsigned)f2bf(b.x) | ((unsigned)f2bf(b.y) << 16);
  o.w = (unsigned)f2bf(b.z) | ((unsigned)f2bf(b.w) << 16);
  *(uint4*)(out + i) = o;
}

// ---------------- fused weight prep: ALL transposes in one launch ----------------
__global__ void k_prep(const float* __restrict__ W1,  const float* __restrict__ W2,
                       const float* __restrict__ EW1, const float* __restrict__ EW2,
                       const float* __restrict__ DW1, const float* __restrict__ DW2,
                       unsigned short* __restrict__ W1T,  unsigned short* __restrict__ W2T,
                       unsigned short* __restrict__ EW1T, unsigned short* __restrict__ EW2T,
                       unsigned short* __restrict__ DW1T, unsigned short* __restrict__ DW2T) {
  const int bid = blockIdx.x;
  const float* in; unsigned short* out; int K, N, tile;
  if (bid < 2048)        { in = W1;  out = W1T;  K = D_IN;  N = D_H;   tile = bid; }
  else if (bid < 3072)   { in = W2;  out = W2T;  K = D_H;   N = D_BOT; tile = bid - 2048; }
  else if (bid < 8192)   { int r = bid - 3072; int e = r >> 9; tile = r & 511;
                           K = D_BOT; N = D_EXP;
                           in = EW1 + (size_t)e * K * N; out = EW1T + (size_t)e * K * N; }
  else if (bid < 13312)  { int r = bid - 8192; int e = r >> 9; tile = r & 511;
                           K = D_EXP; N = D_BOT;
                           in = EW2 + (size_t)e * K * N; out = EW2T + (size_t)e * K * N; }
  else if (bid < 14336)  { in = DW1; out = DW1T; K = D_BOT; N = D_H;   tile = bid - 13312; }
  else                   { in = DW2; out = DW2T; K = D_H;   N = D_IN;  tile = bid - 14336; }
  const int ntx = N >> 5;
  const int n0 = (tile % ntx) * 32, k0 = (tile / ntx) * 32;

  __shared__ float tl[32][33];
  const int tx = threadIdx.x, ty = threadIdx.y;   // 32 x 8
#pragma unroll
  for (int i = 0; i < 4; ++i) {
    int k = ty + i * 8;
    tl[k][tx] = in[(size_t)(k0 + k) * N + n0 + tx];
  }
  __syncthreads();
#pragma unroll
  for (int i = 0; i < 4; ++i) {
    int n = ty + i * 8;
    out[(size_t)(n0 + n) * K + k0 + tx] = f2bf(tl[tx][n]);
  }
}

// ============ R6 4-phase GEMM (bf16-only, exact): C = act(A * WT^T + b) ============
// BK=64, 8 waves (2M x 4N), per-wave (BM/2 x 64). 4 phases per K-tile, one
// 32-col x QR-row quadrant each; double-buffered XOR-16B-swizzled LDS
// (bank-conflict-free, verified R6); stage-all for kt+1 after top barrier;
// vmcnt(0)+barrier once per K-tile; setprio around MFMA clusters.
template <int BM, int BN, bool RELU, bool BF16OUT>
__global__ __launch_bounds__(512, 2) void k_gemm8(
    const unsigned short* __restrict__ A,   // [M][K] bf16
    const unsigned short* __restrict__ WT,  // [N][K] bf16
    const float* __restrict__ bias,         // [N] fp32
    void* __restrict__ Cv,                  // [M][N] bf16 or fp32
    int M, int N, int K) {
  constexpr int WROWS = BM / 2;    // per-wave rows
  constexpr int QR = WROWS / 2;    // quadrant rows
  constexpr int FMq = QR / 16;     // m-frags per quadrant
  constexpr int ACH = BM / 64;     // 8KB stage chunks per K-tile
  constexpr int BCH = BN / 64;

  // XCD-bijective chunk swizzle, y-fastest work order
  const int nby = gridDim.y;
  const int nwg = gridDim.x * nby;
  int orig = blockIdx.x + gridDim.x * blockIdx.y;
  int q = nwg >> 3, r = nwg & 7;
  int xcd = orig & 7, idx = orig >> 3;
  int wg = (xcd < r ? xcd * (q + 1) : r * (q + 1) + (xcd - r) * q) + idx;
  int bx = wg / nby, by = wg % nby;
  const int m0 = bx * BM, n0 = by * BN;

  __shared__ __align__(16) unsigned short As[2][BM * 64];
  __shared__ __align__(16) unsigned short Bs[2][BN * 64];

  const int t = threadIdx.x;
  const int l = t & 63;
  const int w = t >> 6;
  const int wm = w >> 2, wn = w & 3;   // 2M x 4N waves

  // staging coords: thread t covers 16B of each 8KB chunk (64 rows x 128B)
  const int rl = t >> 3;                 // row within chunk
  const int sl16 = (t & 7) ^ (rl & 7);   // inverse-swizzled 16B slot
  const unsigned short* asrc[ACH];
  const unsigned short* bsrc[BCH];
#pragma unroll
  for (int i = 0; i < ACH; ++i)
    asrc[i] = A + (size_t)(m0 + i * 64 + rl) * K + sl16 * 8;
#pragma unroll
  for (int i = 0; i < BCH; ++i)
    bsrc[i] = WT + (size_t)(n0 + i * 64 + rl) * K + sl16 * 8;
  const int dst = t * 8;

  auto STAGE = [&](int kt, int buf) {
#pragma unroll
    for (int i = 0; i < ACH; ++i)
      gload16(asrc[i] + kt * 64, &As[buf][i * 4096 + dst]);
#pragma unroll
    for (int i = 0; i < BCH; ++i)
      gload16(bsrc[i] + kt * 64, &Bs[buf][i * 4096 + dst]);
  };

  f32x4 acc[2][2][FMq][2] = {};   // [qm][qn][fm][fn]
  bf16x8 af[FMq][2];              // current qm's A frags [fm][ks]
  bf16x8 bq[2][2][2];             // both qn's B frags [qn][fn][ks]

  const int la = l & 15;
  const int ko = l >> 4;          // 0..3
  const int arow0 = wm * WROWS + la;
  const int brow0 = wn * 64 + la;

  const int nt = K / 64;
  STAGE(0, 0);

  for (int kt = 0; kt < nt; ++kt) {
    const int cur = kt & 1;
    const char* Ab = (const char*)As[cur];
    const char* Bb = (const char*)Bs[cur];

    asm volatile("s_waitcnt vmcnt(0)" ::: "memory");
    __builtin_amdgcn_s_barrier();
    if (kt + 1 < nt) STAGE(kt + 1, cur ^ 1);
    __builtin_amdgcn_sched_barrier(0);

    // ---- phase 0: read A(q0)+B(q0); MFMA q(0,0) ----
#pragma unroll
    for (int fm = 0; fm < FMq; ++fm)
#pragma unroll
      for (int ks = 0; ks < 2; ++ks) {
        int row = arow0 + fm * 16;
        int s = ks * 4 + ko;
        af[fm][ks] = *(const bf16x8*)(Ab + (row << 7) + ((s ^ (row & 7)) << 4));
      }
#pragma unroll
    for (int fn = 0; fn < 2; ++fn)
#pragma unroll
      for (int ks = 0; ks < 2; ++ks) {
        int row = brow0 + fn * 16;
        int s = ks * 4 + ko;
        bq[0][fn][ks] = *(const bf16x8*)(Bb + (row << 7) + ((s ^ (row & 7)) << 4));
      }
    __builtin_amdgcn_s_setprio(1);
#pragma unroll
    for (int fm = 0; fm < FMq; ++fm)
#pragma unroll
      for (int fn = 0; fn < 2; ++fn)
#pragma unroll
        for (int ks = 0; ks < 2; ++ks)
          acc[0][0][fm][fn] = __builtin_amdgcn_mfma_f32_16x16x32_bf16(
              af[fm][ks], bq[0][fn][ks], acc[0][0][fm][fn], 0, 0, 0);
    __builtin_amdgcn_s_setprio(0);
    __builtin_amdgcn_s_barrier();

    // ---- phase 1: read B(q1); MFMA q(0,1) ----
#pragma unroll
    for (int fn = 0; fn < 2; ++fn)
#pragma unroll
      for (int ks = 0; ks < 2; ++ks) {
        int row = brow0 + 32 + fn * 16;
        int s = ks * 4 + ko;
        bq[1][fn][ks] = *(const bf16x8*)(Bb + (row << 7) + ((s ^ (row & 7)) << 4));
      }
    __builtin_amdgcn_s_setprio(1);
#pragma unroll
    for (int fm = 0; fm < FMq; ++fm)
#pragma unroll
      for (int fn = 0; fn < 2; ++fn)
#pragma unroll
        for (int ks = 0; ks < 2; ++ks)
          acc[0][1][fm][fn] = __builtin_amdgcn_mfma_f32_16x16x32_bf16(
              af[fm][ks], bq[1][fn][ks], acc[0][1][fm][fn], 0, 0, 0);
    __builtin_amdgcn_s_setprio(0);
    __builtin_amdgcn_s_barrier();

    // ---- phase 2: read A(q1); MFMA q(1,0) ----
#pragma unroll
    for (int fm = 0; fm < FMq; ++fm)
#pragma unroll
      for (int ks = 0; ks < 2; ++ks) {
        int row = arow0 + QR + fm * 16;
        int s = ks * 4 + ko;
        af[fm][ks] = *(const bf16x8*)(Ab + (row << 7) + ((s ^ (row & 7)) << 4));
      }
    __builtin_amdgcn_s_setprio(1);
#pragma unroll
    for (int fm = 0; fm < FMq; ++fm)
#pragma unroll
      for (int fn = 0; fn < 2; ++fn)
#pragma unroll
        for (int ks = 0; ks < 2; ++ks)
          acc[1][0][fm][fn] = __builtin_amdgcn_mfma_f32_16x16x32_bf16(
              af[fm][ks], bq[0][fn][ks], acc[1][0][fm][fn], 0, 0, 0);
    __builtin_amdgcn_s_setprio(0);
    __builtin_amdgcn_s_barrier();

    // ---- phase 3: MFMA q(1,1) ----
    __builtin_amdgcn_s_setprio(1);
#pragma unroll
    for (int fm = 0; fm < FMq; ++fm)
#pragma unroll
      for (int fn = 0; fn < 2; ++fn)
#pragma unroll
        for (int ks = 0; ks < 2; ++ks)
          acc[1][1][fm][fn] = __builtin_amdgcn_mfma_f32_16x16x32_bf16(
              af[fm][ks], bq[1][fn][ks], acc[1][1][fm][fn], 0, 0, 0);
    __builtin_amdgcn_s_setprio(0);
  }
  asm volatile("s_waitcnt vmcnt(0)" ::: "memory");

  // epilogue: row = qm*QR + fm*16 + ko*4 + j, col = qn*32 + fn*16 + la
  const int crow0 = m0 + wm * WROWS;
  const int ccol0 = n0 + wn * 64;
#pragma unroll
  for (int qn = 0; qn < 2; ++qn)
#pragma unroll
    for (int fn = 0; fn < 2; ++fn) {
      int c = ccol0 + qn * 32 + fn * 16 + la;
      float bv = bias[c];
#pragma unroll
      for (int qm = 0; qm < 2; ++qm)
#pragma unroll
        for (int fm = 0; fm < FMq; ++fm)
#pragma unroll
          for (int j = 0; j < 4; ++j) {
            int rr = crow0 + qm * QR + fm * 16 + (ko << 2) + j;
            float v = acc[qm][qn][fm][fn][j] + bv;
            if (RELU) v = fmaxf(v, 0.0f);
            if (BF16OUT) ((unsigned short*)Cv)[(size_t)rr * N + c] = f2bf(v);
            else         ((float*)Cv)[(size_t)rr * N + c] = v;
          }
    }
}

// ---------------- round-5 GEMM (L2 / grouped experts) ----------------
template <int TBM, int TBN, int WM, int WN,
          bool RELU, bool BF16OUT, bool GROUPED, bool SCATTER, bool GATHER>
__global__ __launch_bounds__(256) void k_gemm(
    const unsigned short* __restrict__ A,
    const unsigned short* __restrict__ WT,
    const float* __restrict__ bias,
    void* __restrict__ Cv,
    int M, int N, int K,
    const int* __restrict__ starts, const int* __restrict__ counts,
    const int* __restrict__ perm) {
  constexpr int FM = TBM / WM / 16;
  constexpr int FN = TBN / WN / 16;
  constexpr int ALOADS = TBM / 64;
  constexpr int BLOADS = TBN / 64;
  constexpr int LDS_LD = ALOADS + BLOADS;

  const int nby = gridDim.y;
  const int nwg = gridDim.x * nby;
  int orig = blockIdx.x + gridDim.x * blockIdx.y;
  int q = nwg >> 3, r = nwg & 7;
  int xcd = orig & 7, idx = orig >> 3;
  int wg = (xcd < r ? xcd * (q + 1) : r * (q + 1) + (xcd - r) * q) + idx;
  int bx = wg / nby, by = wg % nby;

  int Meff, start = 0, mo;
  const unsigned short* Wp = WT;
  const float* biasp = bias;
  if (GROUPED) {
    int bxr = bx;
    int found = 0;
#pragma unroll
    for (int e = 0; e < N_CLS; ++e) {
      int c = counts[e];
      int nb = (c + TBM - 1) / TBM;
      if (!found && bxr < nb) {
        found = 1; Meff = c; start = starts[e]; mo = bxr * TBM;
        Wp = WT + (size_t)e * N * K; biasp = bias + (size_t)e * N;
      }
      if (!found) bxr -= nb;
    }
    if (!found) return;
    if (!GATHER) A += (size_t)start * K;
  } else {
    Meff = M; mo = bx * TBM;
  }
  const int n0 = by * TBN;

  __shared__ __align__(16) unsigned short As[3][TBM * 32];
  __shared__ __align__(16) unsigned short Bs[3][TBN * 32];

  const int t = threadIdx.x;
  const int l = t & 63;
  const int w = t >> 6;
  const int wm = (w / WN) * (TBM / WM);
  const int wn = (w % WN) * (TBN / WN);

  const int srow = t >> 2;
  const int scol = (t & 3) * 8;
  const unsigned short* ag[ALOADS];
  const unsigned short* bg[BLOADS];
#pragma unroll
  for (int i = 0; i < ALOADS; ++i) {
    int arow = mo + srow + i * 64;
    if (GROUPED) arow = arow < Meff ? arow : Meff - 1;
    int srcrow = GATHER ? perm[start + arow] : arow;
    ag[i] = A + (size_t)srcrow * K + scol;
  }
#pragma unroll
  for (int i = 0; i < BLOADS; ++i)
    bg[i] = Wp + (size_t)(n0 + srow + i * 64) * K + scol;

  auto STAGE = [&](int buf) {
#pragma unroll
    for (int i = 0; i < ALOADS; ++i) {
      gload16(ag[i], &As[buf][t * 8 + i * 2048]);
      ag[i] += 32;
    }
#pragma unroll
    for (int i = 0; i < BLOADS; ++i) {
      gload16(bg[i], &Bs[buf][t * 8 + i * 2048]);
      bg[i] += 32;
    }
  };

  f32x4 acc[FM][FN] = {};

  const int nt = K / 32;
  STAGE(0);
  STAGE(1);
  for (int tI = 0; tI < nt; ++tI) {
    if (tI + 1 < nt)
      asm volatile("s_waitcnt vmcnt(%0)" :: "i"(LDS_LD) : "memory");
    else
      asm volatile("s_waitcnt vmcnt(0)" ::: "memory");
    __builtin_amdgcn_s_barrier();
    __builtin_amdgcn_sched_barrier(0);
    if (tI + 2 < nt) STAGE((tI + 2) % 3);

    const int cur = tI % 3;
    bf16x8 af[FM], bfr[FN];
#pragma unroll
    for (int i = 0; i < FM; ++i)
      af[i] = *(const bf16x8*)(&As[cur][(wm + i * 16 + (l & 15)) * 32 + (l >> 4) * 8]);
#pragma unroll
    for (int i = 0; i < FN; ++i)
      bfr[i] = *(const bf16x8*)(&Bs[cur][(wn + i * 16 + (l & 15)) * 32 + (l >> 4) * 8]);
#pragma unroll
    for (int mi = 0; mi < FM; ++mi)
#pragma unroll
      for (int ni = 0; ni < FN; ++ni)
        acc[mi][ni] = __builtin_amdgcn_mfma_f32_16x16x32_bf16(af[mi], bfr[ni], acc[mi][ni], 0, 0, 0);
  }

  const int cb = n0 + wn + (l & 15);
#pragma unroll
  for (int ni = 0; ni < FN; ++ni) {
    int c = cb + ni * 16;
    float bv = biasp[c];
#pragma unroll
    for (int mi = 0; mi < FM; ++mi) {
#pragma unroll
      for (int j = 0; j < 4; ++j) {
        int rl2 = wm + mi * 16 + ((l >> 4) << 2) + j;
        int re = mo + rl2;
        if (GROUPED && re >= Meff) continue;
        float v = acc[mi][ni][j] + bv;
        if (RELU) v = fmaxf(v, 0.0f);
        int orow;
        if (SCATTER)      orow = perm[start + re];
        else if (GROUPED) orow = start + re;
        else              orow = re;
        if (BF16OUT) ((unsigned short*)Cv)[(size_t)orow * N + c] = f2bf(v);
        else         ((float*)Cv)[(size_t)orow * N + c] = v;
      }
    }
  }
}

#define GX_GROUPED 74   // worst-case sum of ceil(counts[e]/128) over 10 experts

// ---------------- launch ----------------
extern "C" void kernel_launch(void* const* d_in, const int* in_sizes, int n_in,
                              void* d_out, int out_size, void* d_ws, size_t ws_size,
                              hipStream_t stream) {
  const float* x      = (const float*)d_in[0];
  const int*   labels = (const int*)d_in[1];
  const float* W1  = (const float*)d_in[2];  const float* b1  = (const float*)d_in[3];
  const float* W2  = (const float*)d_in[4];  const float* b2  = (const float*)d_in[5];
  const float* EW1 = (const float*)d_in[6];  const float* Eb1 = (const float*)d_in[7];
  const float* EW2 = (const float*)d_in[8];  const float* Eb2 = (const float*)d_in[9];
  const float* DW1 = (const float*)d_in[10]; const float* Db1 = (const float*)d_in[11];
  const float* DW2 = (const float*)d_in[12]; const float* Db2 = (const float*)d_in[13];
  float* out = (float*)d_out;

  char* ws = (char*)d_ws;
  size_t o = 0;
  unsigned short* W1T  = (unsigned short*)(ws + o); o += (size_t)D_IN * D_H * 2;
  unsigned short* W2T  = (unsigned short*)(ws + o); o += (size_t)D_H * D_BOT * 2;
  unsigned short* EW1T = (unsigned short*)(ws + o); o += (size_t)N_CLS * D_BOT * D_EXP * 2;
  unsigned short* EW2T = (unsigned short*)(ws + o); o += (size_t)N_CLS * D_EXP * D_BOT * 2;
  unsigned short* DW1T = (unsigned short*)(ws + o); o += (size_t)D_BOT * D_H * 2;
  unsigned short* DW2T = (unsigned short*)(ws + o); o += (size_t)D_H * D_IN * 2;
  unsigned short* xb   = (unsigned short*)(ws + o); o += (size_t)Bsz * D_IN * 2;
  unsigned short* e1p  = xb;                         // alias: xb dead after L1
  unsigned short* actA = (unsigned short*)(ws + o); o += (size_t)Bsz * D_H * 2;
  unsigned short* h2   = (unsigned short*)(ws + o); o += (size_t)Bsz * D_BOT * 2;
  unsigned short* sel  = (unsigned short*)(ws + o); o += (size_t)Bsz * D_BOT * 2;
  int* counts = (int*)(ws + o);
  int* starts = counts + 16;
  int* perm   = counts + 64;

  // routing metadata (single block)
  k_route<<<1, 1024, 0, stream>>>(labels, counts, starts, perm);

  // all weight transposes in ONE launch
  k_prep<<<16384, dim3(32, 8), 0, stream>>>(W1, W2, EW1, EW2, DW1, DW2,
                                            W1T, W2T, EW1T, EW2T, DW1T, DW2T);

  // input conversion
  k_cvt<<<(Bsz * D_IN) / (256 * 8), 256, 0, stream>>>(x, xb);

  // encoder
  k_gemm8<256, 256, true, true><<<dim3(Bsz / 256, D_H / 256), 512, 0, stream>>>(
      xb, W1T, b1, actA, Bsz, D_H, D_IN);
  k_gemm<128, 64, 4, 1, true, true, false, false, false><<<dim3(Bsz / 128, D_BOT / 64), 256, 0, stream>>>(
      actA, W2T, b2, h2, Bsz, D_BOT, D_H, nullptr, nullptr, nullptr);

  // routed experts; E1 gathers A rows via perm during staging, E2 scatters back
  k_gemm<128, 128, 2, 2, true, true, true, false, true><<<dim3(GX_GROUPED, D_EXP / 128), 256, 0, stream>>>(
      h2, EW1T, Eb1, e1p, Bsz, D_EXP, D_BOT, starts, counts, perm);
  k_gemm<128, 64, 4, 1, true, true, true, true, false><<<dim3(GX_GROUPED, D_BOT / 64), 256, 0, stream>>>(
      e1p, EW2T, Eb2, sel, Bsz, D_BOT, D_EXP, starts, counts, perm);

  // decoder
  k_gemm8<256, 256, true, true><<<dim3(Bsz / 256, D_H / 256), 512, 0, stream>>>(
      sel, DW1T, Db1, actA, Bsz, D_H, D_BOT);
  k_gemm8<128, 256, false, false><<<dim3(Bsz / 128, D_IN / 256), 512, 0, stream>>>(
      actA, DW2T, Db2, out, Bsz, D_IN, D_H);
}

// Round 13
// 236.852 us; speedup vs baseline: 1.1967x; 1.0280x over previous
//
#include <hip/hip_runtime.h>
#include <hip/hip_bf16.h>
#include <stdint.h>

// ---------------- types / helpers ----------------
typedef __attribute__((ext_vector_type(8))) short bf16x8;   // 8 bf16 = 4 VGPRs
typedef __attribute__((ext_vector_type(4))) float f32x4;

__device__ __forceinline__ unsigned short f2bf(float f) {
  unsigned int u = __float_as_uint(f);
  u += 0x7fff + ((u >> 16) & 1);   // round-to-nearest-even
  return (unsigned short)(u >> 16);
}

__device__ __forceinline__ void gload16(const void* g, void* l) {
  __builtin_amdgcn_global_load_lds(
      (const __attribute__((address_space(1))) void*)g,
      (__attribute__((address_space(3))) void*)l, 16, 0, 0);
}

// ---------------- problem constants ----------------
#define Bsz   8192
#define D_IN  1024
#define D_H   2048
#define D_BOT 512
#define D_EXP 1024
#define N_CLS 10

// ---------------- fused prep: weight transposes + routing + x-cvt, ONE launch ----------------
// blocks [0,16384): 32x32 transpose tiles over the 6 weight tensors
// block  16384    : routing (hist+scan+assign), 256 threads x 32 labels
// blocks (16384, 20481): x fp32->bf16, 2048 elems/block
__global__ __launch_bounds__(256) void k_prep_all(
    const float* __restrict__ W1,  const float* __restrict__ W2,
    const float* __restrict__ EW1, const float* __restrict__ EW2,
    const float* __restrict__ DW1, const float* __restrict__ DW2,
    unsigned short* __restrict__ W1T,  unsigned short* __restrict__ W2T,
    unsigned short* __restrict__ EW1T, unsigned short* __restrict__ EW2T,
    unsigned short* __restrict__ DW1T, unsigned short* __restrict__ DW2T,
    const float* __restrict__ x, unsigned short* __restrict__ xb,
    const int* __restrict__ lab, int* __restrict__ counts,
    int* __restrict__ starts, int* __restrict__ perm) {
  const int bid = blockIdx.x;
  const int tx = threadIdx.x, ty = threadIdx.y;   // 32 x 8
  const int t = ty * 32 + tx;

  if (bid < 16384) {
    // ---- weight transpose tile ----
    const float* in; unsigned short* out; int K, N, tile;
    if (bid < 2048)        { in = W1;  out = W1T;  K = D_IN;  N = D_H;   tile = bid; }
    else if (bid < 3072)   { in = W2;  out = W2T;  K = D_H;   N = D_BOT; tile = bid - 2048; }
    else if (bid < 8192)   { int r = bid - 3072; int e = r >> 9; tile = r & 511;
                             K = D_BOT; N = D_EXP;
                             in = EW1 + (size_t)e * K * N; out = EW1T + (size_t)e * K * N; }
    else if (bid < 13312)  { int r = bid - 8192; int e = r >> 9; tile = r & 511;
                             K = D_EXP; N = D_BOT;
                             in = EW2 + (size_t)e * K * N; out = EW2T + (size_t)e * K * N; }
    else if (bid < 14336)  { in = DW1; out = DW1T; K = D_BOT; N = D_H;   tile = bid - 13312; }
    else                   { in = DW2; out = DW2T; K = D_H;   N = D_IN;  tile = bid - 14336; }
    const int ntx = N >> 5;
    const int n0 = (tile % ntx) * 32, k0 = (tile / ntx) * 32;

    __shared__ float tl[32][33];
#pragma unroll
    for (int i = 0; i < 4; ++i) {
      int k = ty + i * 8;
      tl[k][tx] = in[(size_t)(k0 + k) * N + n0 + tx];
    }
    __syncthreads();
#pragma unroll
    for (int i = 0; i < 4; ++i) {
      int n = ty + i * 8;
      out[(size_t)(n0 + n) * K + k0 + tx] = f2bf(tl[tx][n]);
    }
    return;
  }

  if (bid == 16384) {
    // ---- routing: hist + scan + assign ----
    __shared__ int scnt[N_CLS], scur[N_CLS];
    if (t < N_CLS) scnt[t] = 0;
    __syncthreads();
    for (int i = 0; i < 32; ++i)
      atomicAdd(&scnt[lab[t * 32 + i]], 1);
    __syncthreads();
    if (t == 0) {
      int s = 0;
      for (int e = 0; e < N_CLS; ++e) {
        starts[e] = s; scur[e] = s; counts[e] = scnt[e]; s += scnt[e];
      }
    }
    __syncthreads();
    for (int i = 0; i < 32; ++i) {
      int b = t * 32 + i;
      int p = atomicAdd(&scur[lab[b]], 1);
      perm[p] = b;
    }
    return;
  }

  // ---- x fp32 -> bf16 ----
  {
    int i = ((bid - 16385) * 256 + t) * 8;
    const float4* p = (const float4*)(x + i);
    float4 a = p[0], b = p[1];
    uint4 o;
    o.x = (unsigned)f2bf(a.x) | ((unsigned)f2bf(a.y) << 16);
    o.y = (unsigned)f2bf(a.z) | ((unsigned)f2bf(a.w) << 16);
    o.z = (unsigned)f2bf(b.x) | ((unsigned)f2bf(b.y) << 16);
    o.w = (unsigned)f2bf(b.z) | ((unsigned)f2bf(b.w) << 16);
    *(uint4*)(xb + i) = o;
  }
}

// ============ R6 4-phase GEMM (bf16-only, exact): C = act(A * WT^T + b) ============
// BK=64, 8 waves (2M x 4N), per-wave (BM/2 x 64). 4 phases per K-tile, one
// 32-col x QR-row quadrant each; double-buffered XOR-16B-swizzled LDS
// (bank-conflict-free, verified R6); stage-all for kt+1 after top barrier;
// vmcnt(0)+barrier once per K-tile; setprio around MFMA clusters.
template <int BM, int BN, bool RELU, bool BF16OUT>
__global__ __launch_bounds__(512, 2) void k_gemm8(
    const unsigned short* __restrict__ A,   // [M][K] bf16
    const unsigned short* __restrict__ WT,  // [N][K] bf16
    const float* __restrict__ bias,         // [N] fp32
    void* __restrict__ Cv,                  // [M][N] bf16 or fp32
    int M, int N, int K) {
  constexpr int WROWS = BM / 2;    // per-wave rows
  constexpr int QR = WROWS / 2;    // quadrant rows
  constexpr int FMq = QR / 16;     // m-frags per quadrant
  constexpr int ACH = BM / 64;     // 8KB stage chunks per K-tile
  constexpr int BCH = BN / 64;

  // XCD-bijective chunk swizzle, y-fastest work order
  const int nby = gridDim.y;
  const int nwg = gridDim.x * nby;
  int orig = blockIdx.x + gridDim.x * blockIdx.y;
  int q = nwg >> 3, r = nwg & 7;
  int xcd = orig & 7, idx = orig >> 3;
  int wg = (xcd < r ? xcd * (q + 1) : r * (q + 1) + (xcd - r) * q) + idx;
  int bx = wg / nby, by = wg % nby;
  const int m0 = bx * BM, n0 = by * BN;

  __shared__ __align__(16) unsigned short As[2][BM * 64];
  __shared__ __align__(16) unsigned short Bs[2][BN * 64];

  const int t = threadIdx.x;
  const int l = t & 63;
  const int w = t >> 6;
  const int wm = w >> 2, wn = w & 3;   // 2M x 4N waves

  // staging coords: thread t covers 16B of each 8KB chunk (64 rows x 128B)
  const int rl = t >> 3;                 // row within chunk
  const int sl16 = (t & 7) ^ (rl & 7);   // inverse-swizzled 16B slot
  const unsigned short* asrc[ACH];
  const unsigned short* bsrc[BCH];
#pragma unroll
  for (int i = 0; i < ACH; ++i)
    asrc[i] = A + (size_t)(m0 + i * 64 + rl) * K + sl16 * 8;
#pragma unroll
  for (int i = 0; i < BCH; ++i)
    bsrc[i] = WT + (size_t)(n0 + i * 64 + rl) * K + sl16 * 8;
  const int dst = t * 8;

  auto STAGE = [&](int kt, int buf) {
#pragma unroll
    for (int i = 0; i < ACH; ++i)
      gload16(asrc[i] + kt * 64, &As[buf][i * 4096 + dst]);
#pragma unroll
    for (int i = 0; i < BCH; ++i)
      gload16(bsrc[i] + kt * 64, &Bs[buf][i * 4096 + dst]);
  };

  f32x4 acc[2][2][FMq][2] = {};   // [qm][qn][fm][fn]
  bf16x8 af[FMq][2];              // current qm's A frags [fm][ks]
  bf16x8 bq[2][2][2];             // both qn's B frags [qn][fn][ks]

  const int la = l & 15;
  const int ko = l >> 4;          // 0..3
  const int arow0 = wm * WROWS + la;
  const int brow0 = wn * 64 + la;

  const int nt = K / 64;
  STAGE(0, 0);

  for (int kt = 0; kt < nt; ++kt) {
    const int cur = kt & 1;
    const char* Ab = (const char*)As[cur];
    const char* Bb = (const char*)Bs[cur];

    asm volatile("s_waitcnt vmcnt(0)" ::: "memory");
    __builtin_amdgcn_s_barrier();
    if (kt + 1 < nt) STAGE(kt + 1, cur ^ 1);
    __builtin_amdgcn_sched_barrier(0);

    // ---- phase 0: read A(q0)+B(q0); MFMA q(0,0) ----
#pragma unroll
    for (int fm = 0; fm < FMq; ++fm)
#pragma unroll
      for (int ks = 0; ks < 2; ++ks) {
        int row = arow0 + fm * 16;
        int s = ks * 4 + ko;
        af[fm][ks] = *(const bf16x8*)(Ab + (row << 7) + ((s ^ (row & 7)) << 4));
      }
#pragma unroll
    for (int fn = 0; fn < 2; ++fn)
#pragma unroll
      for (int ks = 0; ks < 2; ++ks) {
        int row = brow0 + fn * 16;
        int s = ks * 4 + ko;
        bq[0][fn][ks] = *(const bf16x8*)(Bb + (row << 7) + ((s ^ (row & 7)) << 4));
      }
    __builtin_amdgcn_s_setprio(1);
#pragma unroll
    for (int fm = 0; fm < FMq; ++fm)
#pragma unroll
      for (int fn = 0; fn < 2; ++fn)
#pragma unroll
        for (int ks = 0; ks < 2; ++ks)
          acc[0][0][fm][fn] = __builtin_amdgcn_mfma_f32_16x16x32_bf16(
              af[fm][ks], bq[0][fn][ks], acc[0][0][fm][fn], 0, 0, 0);
    __builtin_amdgcn_s_setprio(0);
    __builtin_amdgcn_s_barrier();

    // ---- phase 1: read B(q1); MFMA q(0,1) ----
#pragma unroll
    for (int fn = 0; fn < 2; ++fn)
#pragma unroll
      for (int ks = 0; ks < 2; ++ks) {
        int row = brow0 + 32 + fn * 16;
        int s = ks * 4 + ko;
        bq[1][fn][ks] = *(const bf16x8*)(Bb + (row << 7) + ((s ^ (row & 7)) << 4));
      }
    __builtin_amdgcn_s_setprio(1);
#pragma unroll
    for (int fm = 0; fm < FMq; ++fm)
#pragma unroll
      for (int fn = 0; fn < 2; ++fn)
#pragma unroll
        for (int ks = 0; ks < 2; ++ks)
          acc[0][1][fm][fn] = __builtin_amdgcn_mfma_f32_16x16x32_bf16(
              af[fm][ks], bq[1][fn][ks], acc[0][1][fm][fn], 0, 0, 0);
    __builtin_amdgcn_s_setprio(0);
    __builtin_amdgcn_s_barrier();

    // ---- phase 2: read A(q1); MFMA q(1,0) ----
#pragma unroll
    for (int fm = 0; fm < FMq; ++fm)
#pragma unroll
      for (int ks = 0; ks < 2; ++ks) {
        int row = arow0 + QR + fm * 16;
        int s = ks * 4 + ko;
        af[fm][ks] = *(const bf16x8*)(Ab + (row << 7) + ((s ^ (row & 7)) << 4));
      }
    __builtin_amdgcn_s_setprio(1);
#pragma unroll
    for (int fm = 0; fm < FMq; ++fm)
#pragma unroll
      for (int fn = 0; fn < 2; ++fn)
#pragma unroll
        for (int ks = 0; ks < 2; ++ks)
          acc[1][0][fm][fn] = __builtin_amdgcn_mfma_f32_16x16x32_bf16(
              af[fm][ks], bq[0][fn][ks], acc[1][0][fm][fn], 0, 0, 0);
    __builtin_amdgcn_s_setprio(0);
    __builtin_amdgcn_s_barrier();

    // ---- phase 3: MFMA q(1,1) ----
    __builtin_amdgcn_s_setprio(1);
#pragma unroll
    for (int fm = 0; fm < FMq; ++fm)
#pragma unroll
      for (int fn = 0; fn < 2; ++fn)
#pragma unroll
        for (int ks = 0; ks < 2; ++ks)
          acc[1][1][fm][fn] = __builtin_amdgcn_mfma_f32_16x16x32_bf16(
              af[fm][ks], bq[1][fn][ks], acc[1][1][fm][fn], 0, 0, 0);
    __builtin_amdgcn_s_setprio(0);
  }
  asm volatile("s_waitcnt vmcnt(0)" ::: "memory");

  // epilogue: row = qm*QR + fm*16 + ko*4 + j, col = qn*32 + fn*16 + la
  const int crow0 = m0 + wm * WROWS;
  const int ccol0 = n0 + wn * 64;
#pragma unroll
  for (int qn = 0; qn < 2; ++qn)
#pragma unroll
    for (int fn = 0; fn < 2; ++fn) {
      int c = ccol0 + qn * 32 + fn * 16 + la;
      float bv = bias[c];
#pragma unroll
      for (int qm = 0; qm < 2; ++qm)
#pragma unroll
        for (int fm = 0; fm < FMq; ++fm)
#pragma unroll
          for (int j = 0; j < 4; ++j) {
            int rr = crow0 + qm * QR + fm * 16 + (ko << 2) + j;
            float v = acc[qm][qn][fm][fn][j] + bv;
            if (RELU) v = fmaxf(v, 0.0f);
            if (BF16OUT) ((unsigned short*)Cv)[(size_t)rr * N + c] = f2bf(v);
            else         ((float*)Cv)[(size_t)rr * N + c] = v;
          }
    }
}

// ---------------- round-5 GEMM (L2 / grouped experts) ----------------
template <int TBM, int TBN, int WM, int WN,
          bool RELU, bool BF16OUT, bool GROUPED, bool SCATTER, bool GATHER>
__global__ __launch_bounds__(256) void k_gemm(
    const unsigned short* __restrict__ A,
    const unsigned short* __restrict__ WT,
    const float* __restrict__ bias,
    void* __restrict__ Cv,
    int M, int N, int K,
    const int* __restrict__ starts, const int* __restrict__ counts,
    const int* __restrict__ perm) {
  constexpr int FM = TBM / WM / 16;
  constexpr int FN = TBN / WN / 16;
  constexpr int ALOADS = TBM / 64;
  constexpr int BLOADS = TBN / 64;
  constexpr int LDS_LD = ALOADS + BLOADS;

  const int nby = gridDim.y;
  const int nwg = gridDim.x * nby;
  int orig = blockIdx.x + gridDim.x * blockIdx.y;
  int q = nwg >> 3, r = nwg & 7;
  int xcd = orig & 7, idx = orig >> 3;
  int wg = (xcd < r ? xcd * (q + 1) : r * (q + 1) + (xcd - r) * q) + idx;
  int bx = wg / nby, by = wg % nby;

  int Meff, start = 0, mo;
  const unsigned short* Wp = WT;
  const float* biasp = bias;
  if (GROUPED) {
    int bxr = bx;
    int found = 0;
#pragma unroll
    for (int e = 0; e < N_CLS; ++e) {
      int c = counts[e];
      int nb = (c + TBM - 1) / TBM;
      if (!found && bxr < nb) {
        found = 1; Meff = c; start = starts[e]; mo = bxr * TBM;
        Wp = WT + (size_t)e * N * K; biasp = bias + (size_t)e * N;
      }
      if (!found) bxr -= nb;
    }
    if (!found) return;
    if (!GATHER) A += (size_t)start * K;
  } else {
    Meff = M; mo = bx * TBM;
  }
  const int n0 = by * TBN;

  __shared__ __align__(16) unsigned short As[3][TBM * 32];
  __shared__ __align__(16) unsigned short Bs[3][TBN * 32];

  const int t = threadIdx.x;
  const int l = t & 63;
  const int w = t >> 6;
  const int wm = (w / WN) * (TBM / WM);
  const int wn = (w % WN) * (TBN / WN);

  const int srow = t >> 2;
  const int scol = (t & 3) * 8;
  const unsigned short* ag[ALOADS];
  const unsigned short* bg[BLOADS];
#pragma unroll
  for (int i = 0; i < ALOADS; ++i) {
    int arow = mo + srow + i * 64;
    if (GROUPED) arow = arow < Meff ? arow : Meff - 1;
    int srcrow = GATHER ? perm[start + arow] : arow;
    ag[i] = A + (size_t)srcrow * K + scol;
  }
#pragma unroll
  for (int i = 0; i < BLOADS; ++i)
    bg[i] = Wp + (size_t)(n0 + srow + i * 64) * K + scol;

  auto STAGE = [&](int buf) {
#pragma unroll
    for (int i = 0; i < ALOADS; ++i) {
      gload16(ag[i], &As[buf][t * 8 + i * 2048]);
      ag[i] += 32;
    }
#pragma unroll
    for (int i = 0; i < BLOADS; ++i) {
      gload16(bg[i], &Bs[buf][t * 8 + i * 2048]);
      bg[i] += 32;
    }
  };

  f32x4 acc[FM][FN] = {};

  const int nt = K / 32;
  STAGE(0);
  STAGE(1);
  for (int tI = 0; tI < nt; ++tI) {
    if (tI + 1 < nt)
      asm volatile("s_waitcnt vmcnt(%0)" :: "i"(LDS_LD) : "memory");
    else
      asm volatile("s_waitcnt vmcnt(0)" ::: "memory");
    __builtin_amdgcn_s_barrier();
    __builtin_amdgcn_sched_barrier(0);
    if (tI + 2 < nt) STAGE((tI + 2) % 3);

    const int cur = tI % 3;
    bf16x8 af[FM], bfr[FN];
#pragma unroll
    for (int i = 0; i < FM; ++i)
      af[i] = *(const bf16x8*)(&As[cur][(wm + i * 16 + (l & 15)) * 32 + (l >> 4) * 8]);
#pragma unroll
    for (int i = 0; i < FN; ++i)
      bfr[i] = *(const bf16x8*)(&Bs[cur][(wn + i * 16 + (l & 15)) * 32 + (l >> 4) * 8]);
#pragma unroll
    for (int mi = 0; mi < FM; ++mi)
#pragma unroll
      for (int ni = 0; ni < FN; ++ni)
        acc[mi][ni] = __builtin_amdgcn_mfma_f32_16x16x32_bf16(af[mi], bfr[ni], acc[mi][ni], 0, 0, 0);
  }

  const int cb = n0 + wn + (l & 15);
#pragma unroll
  for (int ni = 0; ni < FN; ++ni) {
    int c = cb + ni * 16;
    float bv = biasp[c];
#pragma unroll
    for (int mi = 0; mi < FM; ++mi) {
#pragma unroll
      for (int j = 0; j < 4; ++j) {
        int rl2 = wm + mi * 16 + ((l >> 4) << 2) + j;
        int re = mo + rl2;
        if (GROUPED && re >= Meff) continue;
        float v = acc[mi][ni][j] + bv;
        if (RELU) v = fmaxf(v, 0.0f);
        int orow;
        if (SCATTER)      orow = perm[start + re];
        else if (GROUPED) orow = start + re;
        else              orow = re;
        if (BF16OUT) ((unsigned short*)Cv)[(size_t)orow * N + c] = f2bf(v);
        else         ((float*)Cv)[(size_t)orow * N + c] = v;
      }
    }
  }
}

#define GX_GROUPED 74   // worst-case sum of ceil(counts[e]/128) over 10 experts

// ---------------- launch ----------------
extern "C" void kernel_launch(void* const* d_in, const int* in_sizes, int n_in,
                              void* d_out, int out_size, void* d_ws, size_t ws_size,
                              hipStream_t stream) {
  const float* x      = (const float*)d_in[0];
  const int*   labels = (const int*)d_in[1];
  const float* W1  = (const float*)d_in[2];  const float* b1  = (const float*)d_in[3];
  const float* W2  = (const float*)d_in[4];  const float* b2  = (const float*)d_in[5];
  const float* EW1 = (const float*)d_in[6];  const float* Eb1 = (const float*)d_in[7];
  const float* EW2 = (const float*)d_in[8];  const float* Eb2 = (const float*)d_in[9];
  const float* DW1 = (const float*)d_in[10]; const float* Db1 = (const float*)d_in[11];
  const float* DW2 = (const float*)d_in[12]; const float* Db2 = (const float*)d_in[13];
  float* out = (float*)d_out;

  char* ws = (char*)d_ws;
  size_t o = 0;
  unsigned short* W1T  = (unsigned short*)(ws + o); o += (size_t)D_IN * D_H * 2;
  unsigned short* W2T  = (unsigned short*)(ws + o); o += (size_t)D_H * D_BOT * 2;
  unsigned short* EW1T = (unsigned short*)(ws + o); o += (size_t)N_CLS * D_BOT * D_EXP * 2;
  unsigned short* EW2T = (unsigned short*)(ws + o); o += (size_t)N_CLS * D_EXP * D_BOT * 2;
  unsigned short* DW1T = (unsigned short*)(ws + o); o += (size_t)D_BOT * D_H * 2;
  unsigned short* DW2T = (unsigned short*)(ws + o); o += (size_t)D_H * D_IN * 2;
  unsigned short* xb   = (unsigned short*)(ws + o); o += (size_t)Bsz * D_IN * 2;
  unsigned short* e1p  = xb;                         // alias: xb dead after L1
  unsigned short* actA = (unsigned short*)(ws + o); o += (size_t)Bsz * D_H * 2;
  unsigned short* h2   = (unsigned short*)(ws + o); o += (size_t)Bsz * D_BOT * 2;
  unsigned short* sel  = (unsigned short*)(ws + o); o += (size_t)Bsz * D_BOT * 2;
  int* counts = (int*)(ws + o);
  int* starts = counts + 16;
  int* perm   = counts + 64;

  // fused prep: weight transposes + routing + x conversion (ONE launch)
  k_prep_all<<<16384 + 1 + 4096, dim3(32, 8), 0, stream>>>(
      W1, W2, EW1, EW2, DW1, DW2,
      W1T, W2T, EW1T, EW2T, DW1T, DW2T,
      x, xb, labels, counts, starts, perm);

  // encoder
  k_gemm8<256, 256, true, true><<<dim3(Bsz / 256, D_H / 256), 512, 0, stream>>>(
      xb, W1T, b1, actA, Bsz, D_H, D_IN);
  k_gemm<128, 64, 4, 1, true, true, false, false, false><<<dim3(Bsz / 128, D_BOT / 64), 256, 0, stream>>>(
      actA, W2T, b2, h2, Bsz, D_BOT, D_H, nullptr, nullptr, nullptr);

  // routed experts; E1 gathers A rows via perm during staging, E2 scatters back
  k_gemm<128, 128, 2, 2, true, true, true, false, true><<<dim3(GX_GROUPED, D_EXP / 128), 256, 0, stream>>>(
      h2, EW1T, Eb1, e1p, Bsz, D_EXP, D_BOT, starts, counts, perm);
  k_gemm<128, 64, 4, 1, true, true, true, true, false><<<dim3(GX_GROUPED, D_BOT / 64), 256, 0, stream>>>(
      e1p, EW2T, Eb2, sel, Bsz, D_BOT, D_EXP, starts, counts, perm);

  // decoder
  k_gemm8<256, 256, true, true><<<dim3(Bsz / 256, D_H / 256), 512, 0, stream>>>(
      sel, DW1T, Db1, actA, Bsz, D_H, D_BOT);
  k_gemm8<128, 256, false, false><<<dim3(Bsz / 128, D_IN / 256), 512, 0, stream>>>(
      actA, DW2T, Db2, out, Bsz, D_IN, D_H);
}

// Round 14
// 235.596 us; speedup vs baseline: 1.2031x; 1.0053x over previous
//
#include <hip/hip_runtime.h>
#include <hip/hip_bf16.h>
#include <stdint.h>

// ---------------- types / helpers ----------------
typedef __attribute__((ext_vector_type(8))) short bf16x8;   // 8 bf16 = 4 VGPRs
typedef __attribute__((ext_vector_type(4))) float f32x4;

__device__ __forceinline__ unsigned short f2bf(float f) {
  unsigned int u = __float_as_uint(f);
  u += 0x7fff + ((u >> 16) & 1);   // round-to-nearest-even
  return (unsigned short)(u >> 16);
}

__device__ __forceinline__ void gload16(const void* g, void* l) {
  __builtin_amdgcn_global_load_lds(
      (const __attribute__((address_space(1))) void*)g,
      (__attribute__((address_space(3))) void*)l, 16, 0, 0);
}

// ---------------- problem constants ----------------
#define Bsz   8192
#define D_IN  1024
#define D_H   2048
#define D_BOT 512
#define D_EXP 1024
#define N_CLS 10

// ---------------- fused prep: weight transposes + routing + x-cvt, ONE launch ----------------
__global__ __launch_bounds__(256) void k_prep_all(
    const float* __restrict__ W1,  const float* __restrict__ W2,
    const float* __restrict__ EW1, const float* __restrict__ EW2,
    const float* __restrict__ DW1, const float* __restrict__ DW2,
    unsigned short* __restrict__ W1T,  unsigned short* __restrict__ W2T,
    unsigned short* __restrict__ EW1T, unsigned short* __restrict__ EW2T,
    unsigned short* __restrict__ DW1T, unsigned short* __restrict__ DW2T,
    const float* __restrict__ x, unsigned short* __restrict__ xb,
    const int* __restrict__ lab, int* __restrict__ counts,
    int* __restrict__ starts, int* __restrict__ perm) {
  const int bid = blockIdx.x;
  const int tx = threadIdx.x, ty = threadIdx.y;   // 32 x 8
  const int t = ty * 32 + tx;

  if (bid < 16384) {
    const float* in; unsigned short* out; int K, N, tile;
    if (bid < 2048)        { in = W1;  out = W1T;  K = D_IN;  N = D_H;   tile = bid; }
    else if (bid < 3072)   { in = W2;  out = W2T;  K = D_H;   N = D_BOT; tile = bid - 2048; }
    else if (bid < 8192)   { int r = bid - 3072; int e = r >> 9; tile = r & 511;
                             K = D_BOT; N = D_EXP;
                             in = EW1 + (size_t)e * K * N; out = EW1T + (size_t)e * K * N; }
    else if (bid < 13312)  { int r = bid - 8192; int e = r >> 9; tile = r & 511;
                             K = D_EXP; N = D_BOT;
                             in = EW2 + (size_t)e * K * N; out = EW2T + (size_t)e * K * N; }
    else if (bid < 14336)  { in = DW1; out = DW1T; K = D_BOT; N = D_H;   tile = bid - 13312; }
    else                   { in = DW2; out = DW2T; K = D_H;   N = D_IN;  tile = bid - 14336; }
    const int ntx = N >> 5;
    const int n0 = (tile % ntx) * 32, k0 = (tile / ntx) * 32;

    __shared__ float tl[32][33];
#pragma unroll
    for (int i = 0; i < 4; ++i) {
      int k = ty + i * 8;
      tl[k][tx] = in[(size_t)(k0 + k) * N + n0 + tx];
    }
    __syncthreads();
#pragma unroll
    for (int i = 0; i < 4; ++i) {
      int n = ty + i * 8;
      out[(size_t)(n0 + n) * K + k0 + tx] = f2bf(tl[tx][n]);
    }
    return;
  }

  if (bid == 16384) {
    __shared__ int scnt[N_CLS], scur[N_CLS];
    if (t < N_CLS) scnt[t] = 0;
    __syncthreads();
    for (int i = 0; i < 32; ++i)
      atomicAdd(&scnt[lab[t * 32 + i]], 1);
    __syncthreads();
    if (t == 0) {
      int s = 0;
      for (int e = 0; e < N_CLS; ++e) {
        starts[e] = s; scur[e] = s; counts[e] = scnt[e]; s += scnt[e];
      }
    }
    __syncthreads();
    for (int i = 0; i < 32; ++i) {
      int b = t * 32 + i;
      int p = atomicAdd(&scur[lab[b]], 1);
      perm[p] = b;
    }
    return;
  }

  {
    int i = ((bid - 16385) * 256 + t) * 8;
    const float4* p = (const float4*)(x + i);
    float4 a = p[0], b = p[1];
    uint4 o;
    o.x = (unsigned)f2bf(a.x) | ((unsigned)f2bf(a.y) << 16);
    o.y = (unsigned)f2bf(a.z) | ((unsigned)f2bf(a.w) << 16);
    o.z = (unsigned)f2bf(b.x) | ((unsigned)f2bf(b.y) << 16);
    o.w = (unsigned)f2bf(b.z) | ((unsigned)f2bf(b.w) << 16);
    *(uint4*)(xb + i) = o;
  }
}

// ============ m201-faithful 256x256 8-phase GEMM: C = act(A * WT^T + b) ============
// 8 waves (2M x 4N), per-wave 128x64 split across staged halves. BK=64.
// LDS: 8 half-slots x 16KB = 128KB: per K-tile {A0,B0,B1,A1}, dbuf by kt parity.
// Stage stream leads reads by 7 halves (1 half per phase, 2 gloads each);
// vmcnt(6) once per K-tile (phase q3) certifies trailing edge.
// Phases per K-tile: q0: read A-mh0(8)+B-nh0(4), stage A1(kt+1); q1: read
// B-nh1(4), stage A0(kt+2); q2: read A-mh1(8), stage B0(kt+2); q3: no reads,
// stage B1(kt+2), vmcnt(6). Each phase: {reads|stage; barrier; setprio MFMA; barrier}.
template <bool RELU, bool BF16OUT>
__global__ __launch_bounds__(512, 2) void k_g256(
    const unsigned short* __restrict__ A,   // [M][K] bf16
    const unsigned short* __restrict__ WT,  // [N][K] bf16
    const float* __restrict__ bias,         // [N] fp32
    void* __restrict__ Cv,                  // [M][N] bf16 or fp32
    int M, int N, int K) {
  // XCD-bijective chunk swizzle, y-fastest
  const int nby = gridDim.y;
  const int nwg = gridDim.x * nby;
  int orig = blockIdx.x + gridDim.x * blockIdx.y;
  int q = nwg >> 3, r = nwg & 7;
  int xcd = orig & 7, idx = orig >> 3;
  int wg = (xcd < r ? xcd * (q + 1) : r * (q + 1) + (xcd - r) * q) + idx;
  int bx = wg / nby, by = wg % nby;
  const int m0 = bx * 256, n0 = by * 256;

  __shared__ __align__(16) unsigned short lds[8][8192];   // 8 x 16KB

  const int t = threadIdx.x;
  const int l = t & 63;
  const int w = t >> 6;
  const int wm = w >> 2, wn = w & 3;
  const int la = l & 15, ko = l >> 4;

  // stage coords: thread t covers rows {sr, 64+sr} of a 128-row half, 16B chunk c16
  const int sr = t >> 3;
  const int c16 = (t & 7) ^ (sr & 7);     // (64+sr)&7 == sr&7
  const unsigned short* pA0  = A  + (size_t)(m0 + sr) * K + c16 * 8;
  const unsigned short* pA0b = A  + (size_t)(m0 + 64 + sr) * K + c16 * 8;
  const unsigned short* pA1  = A  + (size_t)(m0 + 128 + sr) * K + c16 * 8;
  const unsigned short* pA1b = A  + (size_t)(m0 + 192 + sr) * K + c16 * 8;
  const unsigned short* pB0  = WT + (size_t)(n0 + sr) * K + c16 * 8;
  const unsigned short* pB0b = WT + (size_t)(n0 + 64 + sr) * K + c16 * 8;
  const unsigned short* pB1  = WT + (size_t)(n0 + 128 + sr) * K + c16 * 8;
  const unsigned short* pB1b = WT + (size_t)(n0 + 192 + sr) * K + c16 * 8;
  const int dlo = t * 8, dhi = 4096 + t * 8;

  const int nt = K / 64;

  // ---- prologue: stage halves 0..6 (nt>=8 so all exist) ----
  gload16(pA0, &lds[0][dlo]);  gload16(pA0b, &lds[0][dhi]);
  gload16(pB0, &lds[1][dlo]);  gload16(pB0b, &lds[1][dhi]);
  gload16(pB1, &lds[2][dlo]);  gload16(pB1b, &lds[2][dhi]);
  gload16(pA1, &lds[3][dlo]);  gload16(pA1b, &lds[3][dhi]);
  asm volatile("s_waitcnt vmcnt(4)" ::: "memory");
  gload16(pA0 + 64, &lds[4][dlo]);  gload16(pA0b + 64, &lds[4][dhi]);
  gload16(pB0 + 64, &lds[5][dlo]);  gload16(pB0b + 64, &lds[5][dhi]);
  gload16(pB1 + 64, &lds[6][dlo]);  gload16(pB1b + 64, &lds[6][dhi]);
  asm volatile("s_waitcnt vmcnt(6)" ::: "memory");
  __builtin_amdgcn_s_barrier();

  f32x4 acc[2][4][2][2] = {};   // [mh][fm][nh][fn]
  bf16x8 af[4][2];              // current m-half frags [fm][ks]
  bf16x8 bq[2][2][2];           // [nh][fn][ks]

  for (int kt = 0; kt < nt; ++kt) {
    const int cur = kt & 1;
    const int cs = cur * 4;
    const char* sA0 = (const char*)lds[cs];
    const char* sB0 = (const char*)lds[cs + 1];
    const char* sB1 = (const char*)lds[cs + 2];
    const char* sA1 = (const char*)lds[cs + 3];

    // ===== q0: read A-mh0(8) + B-nh0(4); stage A1(kt+1) -> slot (cur^1)*4+3 =====
#pragma unroll
    for (int fm = 0; fm < 4; ++fm) {
      int rr = wm * 64 + fm * 16 + la;
#pragma unroll
      for (int ks = 0; ks < 2; ++ks)
        af[fm][ks] = *(const bf16x8*)(sA0 + (rr << 7) + (((ks * 4 + ko) ^ (rr & 7)) << 4));
    }
#pragma unroll
    for (int fn = 0; fn < 2; ++fn) {
      int cc = wn * 32 + fn * 16 + la;
#pragma unroll
      for (int ks = 0; ks < 2; ++ks)
        bq[0][fn][ks] = *(const bf16x8*)(sB0 + (cc << 7) + (((ks * 4 + ko) ^ (cc & 7)) << 4));
    }
    if (kt + 1 < nt) {
      int sl = (cur ^ 1) * 4 + 3;
      gload16(pA1 + (kt + 1) * 64, &lds[sl][dlo]);
      gload16(pA1b + (kt + 1) * 64, &lds[sl][dhi]);
    }
    __builtin_amdgcn_sched_barrier(0);
    __builtin_amdgcn_s_barrier();
    __builtin_amdgcn_s_setprio(1);
#pragma unroll
    for (int fm = 0; fm < 4; ++fm)
#pragma unroll
      for (int fn = 0; fn < 2; ++fn)
#pragma unroll
        for (int ks = 0; ks < 2; ++ks)
          acc[0][fm][0][fn] = __builtin_amdgcn_mfma_f32_16x16x32_bf16(
              af[fm][ks], bq[0][fn][ks], acc[0][fm][0][fn], 0, 0, 0);
    __builtin_amdgcn_s_setprio(0);
    __builtin_amdgcn_s_barrier();

    // ===== q1: read B-nh1(4); stage A0(kt+2) -> slot cs+0 =====
#pragma unroll
    for (int fn = 0; fn < 2; ++fn) {
      int cc = wn * 32 + fn * 16 + la;
#pragma unroll
      for (int ks = 0; ks < 2; ++ks)
        bq[1][fn][ks] = *(const bf16x8*)(sB1 + (cc << 7) + (((ks * 4 + ko) ^ (cc & 7)) << 4));
    }
    if (kt + 2 < nt) {
      gload16(pA0 + (kt + 2) * 64, &lds[cs][dlo]);
      gload16(pA0b + (kt + 2) * 64, &lds[cs][dhi]);
    }
    __builtin_amdgcn_sched_barrier(0);
    __builtin_amdgcn_s_barrier();
    __builtin_amdgcn_s_setprio(1);
#pragma unroll
    for (int fm = 0; fm < 4; ++fm)
#pragma unroll
      for (int fn = 0; fn < 2; ++fn)
#pragma unroll
        for (int ks = 0; ks < 2; ++ks)
          acc[0][fm][1][fn] = __builtin_amdgcn_mfma_f32_16x16x32_bf16(
              af[fm][ks], bq[1][fn][ks], acc[0][fm][1][fn], 0, 0, 0);
    __builtin_amdgcn_s_setprio(0);
    __builtin_amdgcn_s_barrier();

    // ===== q2: read A-mh1(8); stage B0(kt+2) -> slot cs+1 =====
#pragma unroll
    for (int fm = 0; fm < 4; ++fm) {
      int rr = wm * 64 + fm * 16 + la;
#pragma unroll
      for (int ks = 0; ks < 2; ++ks)
        af[fm][ks] = *(const bf16x8*)(sA1 + (rr << 7) + (((ks * 4 + ko) ^ (rr & 7)) << 4));
    }
    if (kt + 2 < nt) {
      gload16(pB0 + (kt + 2) * 64, &lds[cs + 1][dlo]);
      gload16(pB0b + (kt + 2) * 64, &lds[cs + 1][dhi]);
    }
    __builtin_amdgcn_sched_barrier(0);
    __builtin_amdgcn_s_barrier();
    __builtin_amdgcn_s_setprio(1);
#pragma unroll
    for (int fm = 0; fm < 4; ++fm)
#pragma unroll
      for (int fn = 0; fn < 2; ++fn)
#pragma unroll
        for (int ks = 0; ks < 2; ++ks)
          acc[1][fm][0][fn] = __builtin_amdgcn_mfma_f32_16x16x32_bf16(
              af[fm][ks], bq[0][fn][ks], acc[1][fm][0][fn], 0, 0, 0);
    __builtin_amdgcn_s_setprio(0);
    __builtin_amdgcn_s_barrier();

    // ===== q3: no reads; stage B1(kt+2) -> slot cs+2; vmcnt(6) =====
    if (kt + 2 < nt) {
      gload16(pB1 + (kt + 2) * 64, &lds[cs + 2][dlo]);
      gload16(pB1b + (kt + 2) * 64, &lds[cs + 2][dhi]);
    }
    __builtin_amdgcn_sched_barrier(0);
    __builtin_amdgcn_s_barrier();
    __builtin_amdgcn_s_setprio(1);
#pragma unroll
    for (int fm = 0; fm < 4; ++fm)
#pragma unroll
      for (int fn = 0; fn < 2; ++fn)
#pragma unroll
        for (int ks = 0; ks < 2; ++ks)
          acc[1][fm][1][fn] = __builtin_amdgcn_mfma_f32_16x16x32_bf16(
              af[fm][ks], bq[1][fn][ks], acc[1][fm][1][fn], 0, 0, 0);
    __builtin_amdgcn_s_setprio(0);
    asm volatile("s_waitcnt vmcnt(6)" ::: "memory");
    __builtin_amdgcn_s_barrier();
  }
  asm volatile("s_waitcnt vmcnt(0)" ::: "memory");

  // epilogue: row = m0 + mh*128 + wm*64 + fm*16 + ko*4 + jj; col = n0 + nh*128 + wn*32 + fn*16 + la
#pragma unroll
  for (int nh = 0; nh < 2; ++nh)
#pragma unroll
    for (int fn = 0; fn < 2; ++fn) {
      int c = n0 + nh * 128 + wn * 32 + fn * 16 + la;
      float bv = bias[c];
#pragma unroll
      for (int mh = 0; mh < 2; ++mh)
#pragma unroll
        for (int fm = 0; fm < 4; ++fm)
#pragma unroll
          for (int jj = 0; jj < 4; ++jj) {
            int rr = m0 + mh * 128 + wm * 64 + fm * 16 + (ko << 2) + jj;
            float v = acc[mh][fm][nh][fn][jj] + bv;
            if (RELU) v = fmaxf(v, 0.0f);
            if (BF16OUT) ((unsigned short*)Cv)[(size_t)rr * N + c] = f2bf(v);
            else         ((float*)Cv)[(size_t)rr * N + c] = v;
          }
    }
}

// ---------------- round-5 GEMM (L2 / grouped experts) ----------------
template <int TBM, int TBN, int WM, int WN,
          bool RELU, bool BF16OUT, bool GROUPED, bool SCATTER, bool GATHER>
__global__ __launch_bounds__(256) void k_gemm(
    const unsigned short* __restrict__ A,
    const unsigned short* __restrict__ WT,
    const float* __restrict__ bias,
    void* __restrict__ Cv,
    int M, int N, int K,
    const int* __restrict__ starts, const int* __restrict__ counts,
    const int* __restrict__ perm) {
  constexpr int FM = TBM / WM / 16;
  constexpr int FN = TBN / WN / 16;
  constexpr int ALOADS = TBM / 64;
  constexpr int BLOADS = TBN / 64;
  constexpr int LDS_LD = ALOADS + BLOADS;

  const int nby = gridDim.y;
  const int nwg = gridDim.x * nby;
  int orig = blockIdx.x + gridDim.x * blockIdx.y;
  int q = nwg >> 3, r = nwg & 7;
  int xcd = orig & 7, idx = orig >> 3;
  int wg = (xcd < r ? xcd * (q + 1) : r * (q + 1) + (xcd - r) * q) + idx;
  int bx = wg / nby, by = wg % nby;

  int Meff, start = 0, mo;
  const unsigned short* Wp = WT;
  const float* biasp = bias;
  if (GROUPED) {
    int bxr = bx;
    int found = 0;
#pragma unroll
    for (int e = 0; e < N_CLS; ++e) {
      int c = counts[e];
      int nb = (c + TBM - 1) / TBM;
      if (!found && bxr < nb) {
        found = 1; Meff = c; start = starts[e]; mo = bxr * TBM;
        Wp = WT + (size_t)e * N * K; biasp = bias + (size_t)e * N;
      }
      if (!found) bxr -= nb;
    }
    if (!found) return;
    if (!GATHER) A += (size_t)start * K;
  } else {
    Meff = M; mo = bx * TBM;
  }
  const int n0 = by * TBN;

  __shared__ __align__(16) unsigned short As[3][TBM * 32];
  __shared__ __align__(16) unsigned short Bs[3][TBN * 32];

  const int t = threadIdx.x;
  const int l = t & 63;
  const int w = t >> 6;
  const int wm = (w / WN) * (TBM / WM);
  const int wn = (w % WN) * (TBN / WN);

  const int srow = t >> 2;
  const int scol = (t & 3) * 8;
  const unsigned short* ag[ALOADS];
  const unsigned short* bg[BLOADS];
#pragma unroll
  for (int i = 0; i < ALOADS; ++i) {
    int arow = mo + srow + i * 64;
    if (GROUPED) arow = arow < Meff ? arow : Meff - 1;
    int srcrow = GATHER ? perm[start + arow] : arow;
    ag[i] = A + (size_t)srcrow * K + scol;
  }
#pragma unroll
  for (int i = 0; i < BLOADS; ++i)
    bg[i] = Wp + (size_t)(n0 + srow + i * 64) * K + scol;

  auto STAGE = [&](int buf) {
#pragma unroll
    for (int i = 0; i < ALOADS; ++i) {
      gload16(ag[i], &As[buf][t * 8 + i * 2048]);
      ag[i] += 32;
    }
#pragma unroll
    for (int i = 0; i < BLOADS; ++i) {
      gload16(bg[i], &Bs[buf][t * 8 + i * 2048]);
      bg[i] += 32;
    }
  };

  f32x4 acc[FM][FN] = {};

  const int nt = K / 32;
  STAGE(0);
  STAGE(1);
  for (int tI = 0; tI < nt; ++tI) {
    if (tI + 1 < nt)
      asm volatile("s_waitcnt vmcnt(%0)" :: "i"(LDS_LD) : "memory");
    else
      asm volatile("s_waitcnt vmcnt(0)" ::: "memory");
    __builtin_amdgcn_s_barrier();
    __builtin_amdgcn_sched_barrier(0);
    if (tI + 2 < nt) STAGE((tI + 2) % 3);

    const int cur = tI % 3;
    bf16x8 af[FM], bfr[FN];
#pragma unroll
    for (int i = 0; i < FM; ++i)
      af[i] = *(const bf16x8*)(&As[cur][(wm + i * 16 + (l & 15)) * 32 + (l >> 4) * 8]);
#pragma unroll
    for (int i = 0; i < FN; ++i)
      bfr[i] = *(const bf16x8*)(&Bs[cur][(wn + i * 16 + (l & 15)) * 32 + (l >> 4) * 8]);
#pragma unroll
    for (int mi = 0; mi < FM; ++mi)
#pragma unroll
      for (int ni = 0; ni < FN; ++ni)
        acc[mi][ni] = __builtin_amdgcn_mfma_f32_16x16x32_bf16(af[mi], bfr[ni], acc[mi][ni], 0, 0, 0);
  }

  const int cb = n0 + wn + (l & 15);
#pragma unroll
  for (int ni = 0; ni < FN; ++ni) {
    int c = cb + ni * 16;
    float bv = biasp[c];
#pragma unroll
    for (int mi = 0; mi < FM; ++mi) {
#pragma unroll
      for (int j = 0; j < 4; ++j) {
        int rl2 = wm + mi * 16 + ((l >> 4) << 2) + j;
        int re = mo + rl2;
        if (GROUPED && re >= Meff) continue;
        float v = acc[mi][ni][j] + bv;
        if (RELU) v = fmaxf(v, 0.0f);
        int orow;
        if (SCATTER)      orow = perm[start + re];
        else if (GROUPED) orow = start + re;
        else              orow = re;
        if (BF16OUT) ((unsigned short*)Cv)[(size_t)orow * N + c] = f2bf(v);
        else         ((float*)Cv)[(size_t)orow * N + c] = v;
      }
    }
  }
}

#define GX_GROUPED 74   // worst-case sum of ceil(counts[e]/128) over 10 experts

// ---------------- launch ----------------
extern "C" void kernel_launch(void* const* d_in, const int* in_sizes, int n_in,
                              void* d_out, int out_size, void* d_ws, size_t ws_size,
                              hipStream_t stream) {
  const float* x      = (const float*)d_in[0];
  const int*   labels = (const int*)d_in[1];
  const float* W1  = (const float*)d_in[2];  const float* b1  = (const float*)d_in[3];
  const float* W2  = (const float*)d_in[4];  const float* b2  = (const float*)d_in[5];
  const float* EW1 = (const float*)d_in[6];  const float* Eb1 = (const float*)d_in[7];
  const float* EW2 = (const float*)d_in[8];  const float* Eb2 = (const float*)d_in[9];
  const float* DW1 = (const float*)d_in[10]; const float* Db1 = (const float*)d_in[11];
  const float* DW2 = (const float*)d_in[12]; const float* Db2 = (const float*)d_in[13];
  float* out = (float*)d_out;

  char* ws = (char*)d_ws;
  size_t o = 0;
  unsigned short* W1T  = (unsigned short*)(ws + o); o += (size_t)D_IN * D_H * 2;
  unsigned short* W2T  = (unsigned short*)(ws + o); o += (size_t)D_H * D_BOT * 2;
  unsigned short* EW1T = (unsigned short*)(ws + o); o += (size_t)N_CLS * D_BOT * D_EXP * 2;
  unsigned short* EW2T = (unsigned short*)(ws + o); o += (size_t)N_CLS * D_EXP * D_BOT * 2;
  unsigned short* DW1T = (unsigned short*)(ws + o); o += (size_t)D_BOT * D_H * 2;
  unsigned short* DW2T = (unsigned short*)(ws + o); o += (size_t)D_H * D_IN * 2;
  unsigned short* xb   = (unsigned short*)(ws + o); o += (size_t)Bsz * D_IN * 2;
  unsigned short* e1p  = xb;                         // alias: xb dead after L1
  unsigned short* actA = (unsigned short*)(ws + o); o += (size_t)Bsz * D_H * 2;
  unsigned short* h2   = (unsigned short*)(ws + o); o += (size_t)Bsz * D_BOT * 2;
  unsigned short* sel  = (unsigned short*)(ws + o); o += (size_t)Bsz * D_BOT * 2;
  int* counts = (int*)(ws + o);
  int* starts = counts + 16;
  int* perm   = counts + 64;

  // fused prep: weight transposes + routing + x conversion (ONE launch)
  k_prep_all<<<16384 + 1 + 4096, dim3(32, 8), 0, stream>>>(
      W1, W2, EW1, EW2, DW1, DW2,
      W1T, W2T, EW1T, EW2T, DW1T, DW2T,
      x, xb, labels, counts, starts, perm);

  // encoder
  k_g256<true, true><<<dim3(Bsz / 256, D_H / 256), 512, 0, stream>>>(
      xb, W1T, b1, actA, Bsz, D_H, D_IN);
  k_gemm<128, 64, 4, 1, true, true, false, false, false><<<dim3(Bsz / 128, D_BOT / 64), 256, 0, stream>>>(
      actA, W2T, b2, h2, Bsz, D_BOT, D_H, nullptr, nullptr, nullptr);

  // routed experts; E1 gathers A rows via perm during staging, E2 scatters back
  k_gemm<128, 128, 2, 2, true, true, true, false, true><<<dim3(GX_GROUPED, D_EXP / 128), 256, 0, stream>>>(
      h2, EW1T, Eb1, e1p, Bsz, D_EXP, D_BOT, starts, counts, perm);
  k_gemm<128, 64, 4, 1, true, true, true, true, false><<<dim3(GX_GROUPED, D_BOT / 64), 256, 0, stream>>>(
      e1p, EW2T, Eb2, sel, Bsz, D_BOT, D_EXP, starts, counts, perm);

  // decoder
  k_g256<true, true><<<dim3(Bsz / 256, D_H / 256), 512, 0, stream>>>(
      sel, DW1T, Db1, actA, Bsz, D_H, D_BOT);
  k_g256<false, false><<<dim3(Bsz / 256, D_IN / 256), 512, 0, stream>>>(
      actA, DW2T, Db2, out, Bsz, D_IN, D_H);
}